// Round 10
// baseline (945.493 us; speedup 1.0000x reference)
//
#include <hip/hip_runtime.h>
#include <hip/hip_bf16.h>

typedef __hip_bfloat16 bf16;
typedef unsigned short u16;

// bf16 bits -> f32 (exact)
static __device__ __forceinline__ float lo16(unsigned u) { return __uint_as_float(u << 16); }
static __device__ __forceinline__ float hi16(unsigned u) { return __uint_as_float(u & 0xFFFF0000u); }
// f32 -> bf16 bits, round-to-nearest-even (no NaNs in this pipeline)
static __device__ __forceinline__ unsigned f2u(float x) {
    unsigned u = __float_as_uint(x);
    return (u + 0x7FFFu + ((u >> 16) & 1u)) >> 16;
}
static __device__ __forceinline__ unsigned pack2(float a, float b) {
    return f2u(a) | (f2u(b) << 16);
}

// ---- problem constants ----
constexpr int D0 = 240, H0 = 144, W0 = 240;
constexpr int V  = D0 * H0 * W0;          // 8,294,400 voxels
constexpr int NPIX = 480 * 640;           // 307,200 pixels
constexpr int D1 = 120, H1 = 72, W1 = 120;
constexpr int N1 = D1 * H1 * W1;          // 1,036,800
constexpr int D2 = 60, H2 = 36, W2 = 60;
constexpr int N2 = D2 * H2 * W2;          // 129,600

// Volume layout: 3 groups x [V][4] bf16 (channel ci = 4*g + c)
constexpr size_t GRP_U16  = (size_t)V * 4;                    // u16 per group (66,355,200 B)
constexpr size_t GRP_BYTES = GRP_U16 * sizeof(u16);           // 66,355,200
constexpr size_t SEG_BYTES = 3 * GRP_BYTES;                   // 199,065,600
constexpr size_t WIN_BYTES = (size_t)V * sizeof(unsigned);    // 33,177,600
constexpr int ZCHUNKS = (int)((SEG_BYTES + WIN_BYTES) / 16);  // 14,515,200 uint4
// Peak ws: SEG_BYTES + GRP_BYTES = 265,420,800 bytes — proven safe.

// ============================================================
// Zero-fill (uint4)
// ============================================================
__global__ void __launch_bounds__(256) kz_zero16(uint4* __restrict__ p, int nchunks) {
    int i = blockIdx.x * 256 + threadIdx.x;
    if (i >= nchunks) return;
    p[i] = make_uint4(0u, 0u, 0u, 0u);
}

// ============================================================
// Scatter: last-write-wins via winner = max(pixel_index+1)
// ============================================================
__global__ void __launch_bounds__(256) kz_scatter_win(const int* __restrict__ depth,
                                                      unsigned* __restrict__ winner) {
    int p = blockIdx.x * 256 + threadIdx.x;
    if (p >= NPIX) return;
    int d = depth[p];
    if (d > 0 && d < V) atomicMax(&winner[d], (unsigned)(p + 1));
}

__global__ void __launch_bounds__(256) kz_scatter_write(const int* __restrict__ depth,
                                                        const unsigned* __restrict__ winner,
                                                        const float* __restrict__ feat,
                                                        u16* __restrict__ seg) {
    int p = blockIdx.x * 256 + threadIdx.x;
    if (p >= NPIX) return;
    int d = depth[p];
    if (d > 0 && d < V && winner[d] == (unsigned)(p + 1)) {
#pragma unroll
        for (int g = 0; g < 3; ++g) {
            uint2 val;
            val.x = pack2(feat[(4 * g + 0) * NPIX + p], feat[(4 * g + 1) * NPIX + p]);
            val.y = pack2(feat[(4 * g + 2) * NPIX + p], feat[(4 * g + 3) * NPIX + p]);
            *(uint2*)(seg + g * GRP_U16 + (size_t)d * 4) = val;
        }
    }
}

// ============================================================
// One-pass avg-pool hole-fill (one group [V][4]):
// thread = 8 consecutive W voxels. 10 column-sums over 9 (d,h) rows,
// 3-tap W window, /27, select where raw==0. Writes to fb != rb (no race).
// ============================================================
__global__ void __launch_bounds__(256) kz_fill1(const u16* __restrict__ rb,
                                                u16* __restrict__ fb) {
    int tid = blockIdx.x * 256 + threadIdx.x;   // grid exact: V/8/256 = 4050
    int w0  = (tid % 30) * 8;
    int row = tid / 30;                          // d*H0 + h
    int h = row % H0;
    int d = row / H0;
    float col[10][4];                            // positions w0-1 .. w0+8
#pragma unroll
    for (int k = 0; k < 10; ++k)
#pragma unroll
        for (int c = 0; c < 4; ++c) col[k][c] = 0.f;
#pragma unroll 1
    for (int dd = -1; dd <= 1; ++dd) {
        int d2 = d + dd;
        if (d2 < 0 || d2 >= D0) continue;
#pragma unroll 1
        for (int dh = -1; dh <= 1; ++dh) {
            int h2 = h + dh;
            if (h2 < 0 || h2 >= H0) continue;
            const u16* rp = rb + (size_t)((d2 * H0 + h2) * W0 + w0) * 4;
#pragma unroll
            for (int q = 0; q < 4; ++q) {        // voxels w0+2q, w0+2q+1
                uint4 X = *(const uint4*)(rp + q * 8);
                col[1 + 2 * q][0] += lo16(X.x); col[1 + 2 * q][1] += hi16(X.x);
                col[1 + 2 * q][2] += lo16(X.y); col[1 + 2 * q][3] += hi16(X.y);
                col[2 + 2 * q][0] += lo16(X.z); col[2 + 2 * q][1] += hi16(X.z);
                col[2 + 2 * q][2] += lo16(X.w); col[2 + 2 * q][3] += hi16(X.w);
            }
            if (w0 > 0) {
                uint2 L = *(const uint2*)(rp - 4);
                col[0][0] += lo16(L.x); col[0][1] += hi16(L.x);
                col[0][2] += lo16(L.y); col[0][3] += hi16(L.y);
            }
            if (w0 < 232) {
                uint2 R = *(const uint2*)(rp + 32);
                col[9][0] += lo16(R.x); col[9][1] += hi16(R.x);
                col[9][2] += lo16(R.y); col[9][3] += hi16(R.y);
            }
        }
    }
    const u16* cp = rb + (size_t)(row * W0 + w0) * 4;   // center row raw (cache-hot)
    u16* op = fb + (size_t)(row * W0 + w0) * 4;
    constexpr float inv27 = 1.0f / 27.0f;
#pragma unroll
    for (int q = 0; q < 4; ++q) {
        uint4 Rv = *(const uint4*)(cp + q * 8);
        // voxel A = w0+2q (window col[2q..2q+2]); voxel B = w0+2q+1 (col[2q+1..2q+3])
        float sA0 = (col[2 * q][0] + col[2 * q + 1][0] + col[2 * q + 2][0]) * inv27;
        float sA1 = (col[2 * q][1] + col[2 * q + 1][1] + col[2 * q + 2][1]) * inv27;
        float sA2 = (col[2 * q][2] + col[2 * q + 1][2] + col[2 * q + 2][2]) * inv27;
        float sA3 = (col[2 * q][3] + col[2 * q + 1][3] + col[2 * q + 2][3]) * inv27;
        float sB0 = (col[2 * q + 1][0] + col[2 * q + 2][0] + col[2 * q + 3][0]) * inv27;
        float sB1 = (col[2 * q + 1][1] + col[2 * q + 2][1] + col[2 * q + 3][1]) * inv27;
        float sB2 = (col[2 * q + 1][2] + col[2 * q + 2][2] + col[2 * q + 3][2]) * inv27;
        float sB3 = (col[2 * q + 1][3] + col[2 * q + 2][3] + col[2 * q + 3][3]) * inv27;
        uint4 O;
        O.x = ((Rv.x & 0x7FFFu) ? (Rv.x & 0xFFFFu) : f2u(sA0))
            | ((((Rv.x >> 16) & 0x7FFFu) ? (Rv.x >> 16) : f2u(sA1)) << 16);
        O.y = ((Rv.y & 0x7FFFu) ? (Rv.y & 0xFFFFu) : f2u(sA2))
            | ((((Rv.y >> 16) & 0x7FFFu) ? (Rv.y >> 16) : f2u(sA3)) << 16);
        O.z = ((Rv.z & 0x7FFFu) ? (Rv.z & 0xFFFFu) : f2u(sB0))
            | ((((Rv.z >> 16) & 0x7FFFu) ? (Rv.z >> 16) : f2u(sB1)) << 16);
        O.w = ((Rv.w & 0x7FFFu) ? (Rv.w & 0xFFFFu) : f2u(sB2))
            | ((((Rv.w >> 16) & 0x7FFFu) ? (Rv.w >> 16) : f2u(sB3)) << 16);
        *(uint4*)(op + q * 8) = O;
    }
}

// ============================================================
// Downsample 1: conv3d 12->4 (k3,s2,p1) ++ maxpool2 of 12ch, relu
// 3 filled group bases, 2 W-outputs per thread, f32 out [16][N1]
// ============================================================
__global__ void __launch_bounds__(256) kz_ds1(const u16* __restrict__ f0,
                                              const u16* __restrict__ f1,
                                              const u16* __restrict__ f2,
                                              const float* __restrict__ w,
                                              float* __restrict__ out) {
    __shared__ float wl[4 * 12 * 27];
    for (int t = threadIdx.x; t < 4 * 12 * 27; t += 256) wl[t] = w[t];
    __syncthreads();
    int idx = blockIdx.x * 256 + threadIdx.x;    // grid exact: N1/2/256 = 2025
    int to = idx % 60;                            // output pair: wo = 2to, 2to+1
    int t  = idx / 60;
    int ho = t % H1;
    int d0 = t / H1;
    int oB = (d0 * H1 + ho) * W1 + 2 * to;
    float accA[4] = {0.f, 0.f, 0.f, 0.f};
    float accB[4] = {0.f, 0.f, 0.f, 0.f};
#pragma unroll 1
    for (int g = 0; g < 3; ++g) {
        const u16* base = (g == 0) ? f0 : ((g == 1) ? f1 : f2);
        const float* wg = wl + (4 * g) * 27;      // + m*324 + c*27 + kd*9 + kh*3 + kw
        float mxA0 = -1e30f, mxA1 = -1e30f, mxA2 = -1e30f, mxA3 = -1e30f;
        float mxB0 = -1e30f, mxB1 = -1e30f, mxB2 = -1e30f, mxB3 = -1e30f;
#pragma unroll 1
        for (int kd = 0; kd < 3; ++kd) {
            int d2 = 2 * d0 - 1 + kd;
            bool dv = (d2 >= 0 && d2 < D0);
#pragma unroll
            for (int kh = 0; kh < 3; ++kh) {
                int h2 = 2 * ho - 1 + kh;
                bool rvv = dv && (h2 >= 0 && h2 < H0);
                float vp[4] = {0.f, 0.f, 0.f, 0.f};   // w2 = 4to-1
                float v0[4] = {0.f, 0.f, 0.f, 0.f};   // 4to
                float v1[4] = {0.f, 0.f, 0.f, 0.f};   // 4to+1
                float v2[4] = {0.f, 0.f, 0.f, 0.f};   // 4to+2
                float v3[4] = {0.f, 0.f, 0.f, 0.f};   // 4to+3
                if (rvv) {
                    size_t r2 = (size_t)((d2 * H0 + h2) * W0 + 4 * to);
                    uint4 A = *(const uint4*)(base + r2 * 4);        // vox 4to,4to+1
                    uint4 B = *(const uint4*)(base + (r2 + 2) * 4);  // vox 4to+2,4to+3
                    v0[0] = lo16(A.x); v0[1] = hi16(A.x); v0[2] = lo16(A.y); v0[3] = hi16(A.y);
                    v1[0] = lo16(A.z); v1[1] = hi16(A.z); v1[2] = lo16(A.w); v1[3] = hi16(A.w);
                    v2[0] = lo16(B.x); v2[1] = hi16(B.x); v2[2] = lo16(B.y); v2[3] = hi16(B.y);
                    v3[0] = lo16(B.z); v3[1] = hi16(B.z); v3[2] = lo16(B.w); v3[3] = hi16(B.w);
                    if (to > 0) {
                        uint2 P = *(const uint2*)(base + (r2 - 1) * 4);
                        vp[0] = lo16(P.x); vp[1] = hi16(P.x); vp[2] = lo16(P.y); vp[3] = hi16(P.y);
                    }
                }
                const float* wk = wg + kd * 9 + kh * 3;
#pragma unroll
                for (int m = 0; m < 4; ++m) {
                    const float* wm = wk + m * 324;
#pragma unroll
                    for (int c = 0; c < 4; ++c) {
                        float w0c = wm[c * 27], w1c = wm[c * 27 + 1], w2c = wm[c * 27 + 2];
                        accA[m] += vp[c] * w0c + v0[c] * w1c + v1[c] * w2c;
                        accB[m] += v1[c] * w0c + v2[c] * w1c + v3[c] * w2c;
                    }
                }
                if (kd >= 1 && kh >= 1) {        // pool = inner 2x2x2
                    mxA0 = fmaxf(mxA0, fmaxf(v0[0], v1[0]));
                    mxA1 = fmaxf(mxA1, fmaxf(v0[1], v1[1]));
                    mxA2 = fmaxf(mxA2, fmaxf(v0[2], v1[2]));
                    mxA3 = fmaxf(mxA3, fmaxf(v0[3], v1[3]));
                    mxB0 = fmaxf(mxB0, fmaxf(v2[0], v3[0]));
                    mxB1 = fmaxf(mxB1, fmaxf(v2[1], v3[1]));
                    mxB2 = fmaxf(mxB2, fmaxf(v2[2], v3[2]));
                    mxB3 = fmaxf(mxB3, fmaxf(v2[3], v3[3]));
                }
            }
        }
        *(float2*)(out + (size_t)(4 + 4 * g + 0) * N1 + oB) = make_float2(fmaxf(mxA0, 0.f), fmaxf(mxB0, 0.f));
        *(float2*)(out + (size_t)(4 + 4 * g + 1) * N1 + oB) = make_float2(fmaxf(mxA1, 0.f), fmaxf(mxB1, 0.f));
        *(float2*)(out + (size_t)(4 + 4 * g + 2) * N1 + oB) = make_float2(fmaxf(mxA2, 0.f), fmaxf(mxB2, 0.f));
        *(float2*)(out + (size_t)(4 + 4 * g + 3) * N1 + oB) = make_float2(fmaxf(mxA3, 0.f), fmaxf(mxB3, 0.f));
    }
#pragma unroll
    for (int m = 0; m < 4; ++m)
        *(float2*)(out + (size_t)m * N1 + oB) = make_float2(fmaxf(accA[m], 0.f), fmaxf(accB[m], 0.f));
}

// ============================================================
// Downsample 2: conv3d 16->16 (k3,s2,p1) ++ maxpool2 of 16ch, relu
// f32 in/out. Paired W loads (float2).
// ============================================================
__global__ void __launch_bounds__(256) kz_ds2(const float* __restrict__ in,
                                              const float* __restrict__ w,
                                              float* __restrict__ out) {
    __shared__ float wl[16 * 16 * 27];
    for (int t = threadIdx.x; t < 16 * 16 * 27; t += 256) wl[t] = w[t];
    __syncthreads();
    int o = blockIdx.x * 256 + threadIdx.x;
    if (o >= N2) return;
    int wo = o % W2;
    int t  = o / W2;
    int ho = t % H2;
    int d0 = t / H2;
    float acc[16];
#pragma unroll
    for (int m = 0; m < 16; ++m) acc[m] = 0.f;
#pragma unroll 1
    for (int ci = 0; ci < 16; ++ci) {
        const float* base = in + ci * N1;
        const float* wci = wl + ci * 27;
        float mx = -1e30f;
#pragma unroll 1
        for (int kd = 0; kd < 3; ++kd) {
            int d2 = 2 * d0 - 1 + kd;
            bool dv = (d2 >= 0 && d2 < D1);
#pragma unroll
            for (int kh = 0; kh < 3; ++kh) {
                int h2 = 2 * ho - 1 + kh;
                bool rvv = dv && (h2 >= 0 && h2 < H1);
                float vm1 = 0.f, v0 = 0.f, v1 = 0.f;
                if (rvv) {
                    int r2 = (d2 * H1 + h2) * W1 + 2 * wo;
                    float2 pb = *(const float2*)(base + r2);
                    v0 = pb.x; v1 = pb.y;
                    if (wo > 0) {
                        float2 pa = *(const float2*)(base + r2 - 2);
                        vm1 = pa.y;
                    }
                }
                const float* wk = wci + kd * 9 + kh * 3;
#pragma unroll
                for (int m = 0; m < 16; ++m)
                    acc[m] += vm1 * wk[m * 432] + v0 * wk[m * 432 + 1] + v1 * wk[m * 432 + 2];
                if (kd >= 1 && kh >= 1) mx = fmaxf(mx, fmaxf(v0, v1));
            }
        }
        out[(16 + ci) * N2 + o] = fmaxf(mx, 0.f);
    }
#pragma unroll
    for (int m = 0; m < 16; ++m) out[m * N2 + o] = fmaxf(acc[m], 0.f);
}

// ============================================================
// Pointwise (1x1x1) conv, optional residual, relu, f32 out
// ============================================================
template <int CIN, int COUT, bool HASRES>
__global__ void __launch_bounds__(256) kz_pw(const float* __restrict__ in,
                                             const float* __restrict__ w,
                                             const float* __restrict__ res,
                                             float* __restrict__ outf, int N) {
    __shared__ float wl[CIN * COUT];
    for (int t = threadIdx.x; t < CIN * COUT; t += 256) wl[t] = w[t];
    __syncthreads();
    int o = blockIdx.x * 256 + threadIdx.x;
    if (o >= N) return;
    float acc[COUT];
#pragma unroll
    for (int m = 0; m < COUT; ++m) acc[m] = 0.f;
    for (int ci = 0; ci < CIN; ++ci) {
        float v = in[ci * N + o];
#pragma unroll
        for (int m = 0; m < COUT; ++m) acc[m] += v * wl[m * CIN + ci];
    }
#pragma unroll
    for (int m = 0; m < COUT; ++m) {
        float r = acc[m];
        if (HASRES) r += res[m * N + o];
        outf[m * N + o] = fmaxf(r, 0.f);
    }
}

// ============================================================
// Bottleneck middle conv: C->C, kernel (KD,KH,KW) same-pad on >1 dims,
// + bias + up to 2 residual adds + relu. f32 in/out.
// ============================================================
template <int C, int KD, int KH, int KW, int NADD>
__global__ void __launch_bounds__(256) kz_bconv(const float* __restrict__ in,
                                                const float* __restrict__ w,
                                                const float* __restrict__ b,
                                                const float* __restrict__ add1,
                                                const float* __restrict__ add2,
                                                float* __restrict__ out,
                                                int Dd, int Hh, int Ww, int N) {
    __shared__ float wl[C * C * KD * KH * KW];
    __shared__ float bl[C];
    for (int t = threadIdx.x; t < C * C * KD * KH * KW; t += 256) wl[t] = w[t];
    if (threadIdx.x < C) bl[threadIdx.x] = b[threadIdx.x];
    __syncthreads();
    int o = blockIdx.x * 256 + threadIdx.x;
    if (o >= N) return;
    int wo = o % Ww;
    int t  = o / Ww;
    int ho = t % Hh;
    int d0 = t / Hh;
    float acc[C];
#pragma unroll
    for (int m = 0; m < C; ++m) acc[m] = bl[m];
#pragma unroll 1
    for (int ci = 0; ci < C; ++ci) {
        const float* base = in + ci * N;
        const float* wci = wl + ci * KD * KH * KW;
#pragma unroll
        for (int kd = 0; kd < KD; ++kd) {
            int d2 = d0 + kd - KD / 2;
            if (d2 < 0 || d2 >= Dd) continue;
#pragma unroll
            for (int kh = 0; kh < KH; ++kh) {
                int h2 = ho + kh - KH / 2;
                if (h2 < 0 || h2 >= Hh) continue;
#pragma unroll
                for (int kw = 0; kw < KW; ++kw) {
                    int w2 = wo + kw - KW / 2;
                    if (w2 < 0 || w2 >= Ww) continue;
                    float v = base[(d2 * Hh + h2) * Ww + w2];
                    int wi = kd * KH * KW + kh * KW + kw;
#pragma unroll
                    for (int m = 0; m < C; ++m)
                        acc[m] += v * wci[m * C * KD * KH * KW + wi];
                }
            }
        }
    }
#pragma unroll
    for (int m = 0; m < C; ++m) {
        float r = acc[m];
        if (NADD >= 1) r += add1[m * N + o];
        if (NADD >= 2) r += add2[m * N + o];
        out[m * N + o] = fmaxf(r, 0.f);
    }
}

// ============================================================
extern "C" void kernel_launch(void* const* d_in, const int* in_sizes, int n_in,
                              void* d_out, int out_size, void* d_ws, size_t ws_size,
                              hipStream_t stream) {
    const float* feat   = (const float*)d_in[0];
    const int*   depth  = (const int*)d_in[1];
    const float* w_ds1  = (const float*)d_in[2];
    const float* b1_win = (const float*)d_in[3];
    const float* b1w133 = (const float*)d_in[4];
    const float* b1b133 = (const float*)d_in[5];
    const float* b1w331 = (const float*)d_in[6];
    const float* b1b331 = (const float*)d_in[7];
    const float* b1w313 = (const float*)d_in[8];
    const float* b1b313 = (const float*)d_in[9];
    const float* b1wout = (const float*)d_in[10];
    const float* w_ds2  = (const float*)d_in[11];
    const float* b2_win = (const float*)d_in[12];
    const float* b2w133 = (const float*)d_in[13];
    const float* b2b133 = (const float*)d_in[14];
    const float* b2w331 = (const float*)d_in[15];
    const float* b2b331 = (const float*)d_in[16];
    const float* b2w313 = (const float*)d_in[17];
    const float* b2b313 = (const float*)d_in[18];
    const float* b2wout = (const float*)d_in[19];

    char* base = (char*)d_ws;

    // --- Region layout (time-shared; peak = 265.4 MB, proven safe) ---
    // Phase A: raw volume [0, 199) = 3 groups x 66.35 MB; winner [199, 232.2).
    u16* raw0 = (u16*)base;
    u16* raw1 = (u16*)(base + GRP_BYTES);
    u16* raw2 = (u16*)(base + 2 * GRP_BYTES);
    unsigned* winner = (unsigned*)(base + SEG_BYTES);
    // Phase B: filled groups rotate into dead space:
    u16* fil0 = (u16*)(base + SEG_BYTES);      // [199, 265) — winner dead after scatter
    u16* fil1 = (u16*)base;                    // [0, 66)   — raw g0 dead after fill g0
    u16* fil2 = (u16*)(base + GRP_BYTES);      // [66, 132) — raw g1 dead after fill g1
    // Phase C: ds1 output x1 -> [132, 199) (raw g2 dead after fill g2)
    float* x1 = (float*)(base + 2 * GRP_BYTES);
    // Phase D (fil* dead after ds1): y0..y3 in [0, 66); x1b -> [66, 132)
    float* y0  = (float*)base;
    float* y1  = y0 + 4 * N1;
    float* y2  = y1 + 4 * N1;
    float* y3  = y2 + 4 * N1;
    float* x1b = (float*)(base + GRP_BYTES);
    // Phase E (y dead): x2, z* in [0, 33)
    float* x2 = (float*)base;
    float* z0 = x2 + 32 * N2;
    float* z1 = z0 + 8 * N2;
    float* z2 = z1 + 8 * N2;
    float* z3 = z2 + 8 * N2;

    float* out = (float*)d_out;   // reference output dtype is float32

    // 1. zero raw volume + winner (contiguous)
    kz_zero16<<<ZCHUNKS / 256, 256, 0, stream>>>((uint4*)base, ZCHUNKS);

    // 2. deterministic last-write-wins scatter
    kz_scatter_win  <<<NPIX / 256, 256, 0, stream>>>(depth, winner);
    kz_scatter_write<<<NPIX / 256, 256, 0, stream>>>(depth, winner, feat, raw0);

    // 3. one-pass avg-pool hole-fill per group (out-of-place, rotating regions)
    kz_fill1<<<(V / 8) / 256, 256, 0, stream>>>(raw0, fil0);
    kz_fill1<<<(V / 8) / 256, 256, 0, stream>>>(raw1, fil1);
    kz_fill1<<<(V / 8) / 256, 256, 0, stream>>>(raw2, fil2);

    // 4. downsample 1 -> x1 f32 [16][N1]
    kz_ds1<<<(N1 / 2) / 256, 256, 0, stream>>>(fil0, fil1, fil2, w_ds1, x1);

    // 5. bottleneck 1 (ch16, mid4, spatial 120x72x120)
    kz_pw<16, 4, false><<<N1 / 256, 256, 0, stream>>>(x1, b1_win, nullptr, y0, N1);
    kz_bconv<4, 1, 3, 3, 0><<<N1 / 256, 256, 0, stream>>>(y0, b1w133, b1b133, nullptr, nullptr, y1, D1, H1, W1, N1);
    kz_bconv<4, 3, 3, 1, 1><<<N1 / 256, 256, 0, stream>>>(y1, b1w331, b1b331, y1, nullptr, y2, D1, H1, W1, N1);
    kz_bconv<4, 3, 1, 3, 2><<<N1 / 256, 256, 0, stream>>>(y2, b1w313, b1b313, y2, y1, y3, D1, H1, W1, N1);
    kz_pw<4, 16, true><<<N1 / 256, 256, 0, stream>>>(y3, b1wout, x1, x1b, N1);

    // 6. downsample 2 -> x2 f32 [32][N2]
    kz_ds2<<<(N2 + 255) / 256, 256, 0, stream>>>(x1b, w_ds2, x2);

    // 7. bottleneck 2 (ch32, mid8, spatial 60x36x60) -> f32 d_out
    kz_pw<32, 8, false><<<(N2 + 255) / 256, 256, 0, stream>>>(x2, b2_win, nullptr, z0, N2);
    kz_bconv<8, 1, 3, 3, 0><<<(N2 + 255) / 256, 256, 0, stream>>>(z0, b2w133, b2b133, nullptr, nullptr, z1, D2, H2, W2, N2);
    kz_bconv<8, 3, 3, 1, 1><<<(N2 + 255) / 256, 256, 0, stream>>>(z1, b2w331, b2b331, z1, nullptr, z2, D2, H2, W2, N2);
    kz_bconv<8, 3, 1, 3, 2><<<(N2 + 255) / 256, 256, 0, stream>>>(z2, b2w313, b2b313, z2, z1, z3, D2, H2, W2, N2);
    kz_pw<8, 32, true><<<(N2 + 255) / 256, 256, 0, stream>>>(z3, b2wout, x2, out, N2);

    (void)in_sizes; (void)n_in; (void)out_size; (void)ws_size;
}

// Round 11
// 834.068 us; speedup vs baseline: 1.1336x; 1.1336x over previous
//
#include <hip/hip_runtime.h>
#include <hip/hip_bf16.h>

typedef __hip_bfloat16 bf16;
typedef unsigned short u16;

// bf16 bits -> f32 (exact)
static __device__ __forceinline__ float lo16(unsigned u) { return __uint_as_float(u << 16); }
static __device__ __forceinline__ float hi16(unsigned u) { return __uint_as_float(u & 0xFFFF0000u); }
// f32 -> bf16 bits, round-to-nearest-even (no NaNs in this pipeline)
static __device__ __forceinline__ unsigned f2u(float x) {
    unsigned u = __float_as_uint(x);
    return (u + 0x7FFFu + ((u >> 16) & 1u)) >> 16;
}
static __device__ __forceinline__ unsigned pack2(float a, float b) {
    return f2u(a) | (f2u(b) << 16);
}

// ---- problem constants ----
constexpr int D0 = 240, H0 = 144, W0 = 240;
constexpr int V  = D0 * H0 * W0;          // 8,294,400 voxels
constexpr int NPIX = 480 * 640;           // 307,200 pixels
constexpr int D1 = 120, H1 = 72, W1 = 120;
constexpr int N1 = D1 * H1 * W1;          // 1,036,800
constexpr int D2 = 60, H2 = 36, W2 = 60;
constexpr int N2 = D2 * H2 * W2;          // 129,600

// Volume layout: 3 groups x [V][4] bf16 (channel ci = 4*g + c)
constexpr size_t GRP_U16  = (size_t)V * 4;                    // u16 per group
constexpr size_t GRP_BYTES = GRP_U16 * sizeof(u16);           // 66,355,200
constexpr size_t SEG_BYTES = 3 * GRP_BYTES;                   // 199,065,600
constexpr size_t WIN_BYTES = (size_t)V * sizeof(unsigned);    // 33,177,600
constexpr int ZCHUNKS = (int)((SEG_BYTES + WIN_BYTES) / 16);  // 14,515,200 uint4
// Peak ws: SEG_BYTES + GRP_BYTES = 265,420,800 bytes — proven safe.

// ============================================================
// Zero-fill (uint4)
// ============================================================
__global__ void __launch_bounds__(256) kz_zero16(uint4* __restrict__ p, int nchunks) {
    int i = blockIdx.x * 256 + threadIdx.x;
    if (i >= nchunks) return;
    p[i] = make_uint4(0u, 0u, 0u, 0u);
}

// ============================================================
// Scatter: last-write-wins via winner = max(pixel_index+1)
// ============================================================
__global__ void __launch_bounds__(256) kz_scatter_win(const int* __restrict__ depth,
                                                      unsigned* __restrict__ winner) {
    int p = blockIdx.x * 256 + threadIdx.x;
    if (p >= NPIX) return;
    int d = depth[p];
    if (d > 0 && d < V) atomicMax(&winner[d], (unsigned)(p + 1));
}

__global__ void __launch_bounds__(256) kz_scatter_write(const int* __restrict__ depth,
                                                        const unsigned* __restrict__ winner,
                                                        const float* __restrict__ feat,
                                                        u16* __restrict__ seg) {
    int p = blockIdx.x * 256 + threadIdx.x;
    if (p >= NPIX) return;
    int d = depth[p];
    if (d > 0 && d < V && winner[d] == (unsigned)(p + 1)) {
#pragma unroll
        for (int g = 0; g < 3; ++g) {
            uint2 val;
            val.x = pack2(feat[(4 * g + 0) * NPIX + p], feat[(4 * g + 1) * NPIX + p]);
            val.y = pack2(feat[(4 * g + 2) * NPIX + p], feat[(4 * g + 3) * NPIX + p]);
            *(uint2*)(seg + g * GRP_U16 + (size_t)d * 4) = val;
        }
    }
}

// ============================================================
// Fill pass A (one group [V][4]): 3-tap W sums -> bf16 tmp, 2 voxels/thread
// (R9-proven version)
// ============================================================
__global__ void __launch_bounds__(256) kz_sumwI(const u16* __restrict__ sb,
                                                u16* __restrict__ tb) {
    int r = blockIdx.x * 256 + threadIdx.x;      // grid exact: V/2/256
    int i = 2 * r;                                // even voxel index
    int w = i % W0;                               // even
    uint4 X = *(const uint4*)(sb + (size_t)i * 4);
    float x0[4] = {lo16(X.x), hi16(X.x), lo16(X.y), hi16(X.y)};
    float x1[4] = {lo16(X.z), hi16(X.z), lo16(X.w), hi16(X.w)};
    float l[4] = {0.f, 0.f, 0.f, 0.f}, rr[4] = {0.f, 0.f, 0.f, 0.f};
    if (w > 0) {
        uint2 L = *(const uint2*)(sb + (size_t)(i - 1) * 4);
        l[0] = lo16(L.x); l[1] = hi16(L.x); l[2] = lo16(L.y); l[3] = hi16(L.y);
    }
    if (w < 238) {
        uint2 R = *(const uint2*)(sb + (size_t)(i + 2) * 4);
        rr[0] = lo16(R.x); rr[1] = hi16(R.x); rr[2] = lo16(R.y); rr[3] = hi16(R.y);
    }
    uint4 O;
    O.x = pack2(l[0] + x0[0] + x1[0], l[1] + x0[1] + x1[1]);
    O.y = pack2(l[2] + x0[2] + x1[2], l[3] + x0[3] + x1[3]);
    O.z = pack2(x0[0] + x1[0] + rr[0], x0[1] + x1[1] + rr[1]);
    O.w = pack2(x0[2] + x1[2] + rr[2], x0[3] + x1[3] + rr[3]);
    *(uint4*)(tb + (size_t)i * 4) = O;
}

// ============================================================
// Fill pass B (one group, IN-PLACE): 9-tap (d,h) sum of W row-sums, /27,
// only where raw==0. (R9-proven version)
// ============================================================
__global__ void __launch_bounds__(256) kz_fillI(u16* __restrict__ rb,
                                                const u16* __restrict__ tb) {
    int r = blockIdx.x * 256 + threadIdx.x;
    int i = 2 * r;
    uint4 R = *(const uint4*)(rb + (size_t)i * 4);
    bool z[8];
    z[0] = (R.x & 0x7FFFu) == 0;          z[1] = ((R.x >> 16) & 0x7FFFu) == 0;
    z[2] = (R.y & 0x7FFFu) == 0;          z[3] = ((R.y >> 16) & 0x7FFFu) == 0;
    z[4] = (R.z & 0x7FFFu) == 0;          z[5] = ((R.z >> 16) & 0x7FFFu) == 0;
    z[6] = (R.w & 0x7FFFu) == 0;          z[7] = ((R.w >> 16) & 0x7FFFu) == 0;
    if (!(z[0] | z[1] | z[2] | z[3] | z[4] | z[5] | z[6] | z[7])) return;
    int w = i % W0;
    int t = i / W0;
    int h = t % H0;
    int d = t / H0;
    float s[8] = {0.f, 0.f, 0.f, 0.f, 0.f, 0.f, 0.f, 0.f};
#pragma unroll
    for (int dd = -1; dd <= 1; ++dd) {
        int d2 = d + dd;
        if (d2 < 0 || d2 >= D0) continue;
#pragma unroll
        for (int dh = -1; dh <= 1; ++dh) {
            int h2 = h + dh;
            if (h2 < 0 || h2 >= H0) continue;
            uint4 T = *(const uint4*)(tb + (size_t)((d2 * H0 + h2) * W0 + w) * 4);
            s[0] += lo16(T.x); s[1] += hi16(T.x); s[2] += lo16(T.y); s[3] += hi16(T.y);
            s[4] += lo16(T.z); s[5] += hi16(T.z); s[6] += lo16(T.w); s[7] += hi16(T.w);
        }
    }
    constexpr float inv27 = 1.0f / 27.0f;
    uint4 O;
    O.x = (z[0] ? f2u(s[0] * inv27) : (R.x & 0xFFFFu)) | ((z[1] ? f2u(s[1] * inv27) : (R.x >> 16)) << 16);
    O.y = (z[2] ? f2u(s[2] * inv27) : (R.y & 0xFFFFu)) | ((z[3] ? f2u(s[3] * inv27) : (R.y >> 16)) << 16);
    O.z = (z[4] ? f2u(s[4] * inv27) : (R.z & 0xFFFFu)) | ((z[5] ? f2u(s[5] * inv27) : (R.z >> 16)) << 16);
    O.w = (z[6] ? f2u(s[6] * inv27) : (R.w & 0xFFFFu)) | ((z[7] ? f2u(s[7] * inv27) : (R.w >> 16)) << 16);
    *(uint4*)(rb + (size_t)i * 4) = O;
}

// ============================================================
// Downsample 1 (R9-proven structure): conv 12->4 (k3,s2,p1) ++ maxpool2, relu
// interleaved bf16 volume in, f32 weights, OUT: x1 interleaved [N1][16] f32
// ============================================================
__global__ void __launch_bounds__(256) kz_ds1(const u16* __restrict__ seg,
                                              const float* __restrict__ w,
                                              float* __restrict__ x1i) {
    __shared__ float wl[4 * 12 * 27];
    for (int t = threadIdx.x; t < 4 * 12 * 27; t += 256) wl[t] = w[t];
    __syncthreads();
    int o = blockIdx.x * 256 + threadIdx.x;   // grid exact: N1/256 = 4050
    int wo = o % W1;
    int t  = o / W1;
    int ho = t % H1;
    int d0 = t / H1;
    float acc[4] = {0.f, 0.f, 0.f, 0.f};
    float* xo = x1i + (size_t)o * 16;
#pragma unroll 1
    for (int g = 0; g < 3; ++g) {
        const u16* base = seg + (size_t)g * GRP_U16;
        const float* wg = wl + (4 * g) * 27;
        float mx0 = -1e30f, mx1 = -1e30f, mx2 = -1e30f, mx3 = -1e30f;
#pragma unroll 1
        for (int kd = 0; kd < 3; ++kd) {
            int d2 = 2 * d0 - 1 + kd;
            bool dv = (d2 >= 0 && d2 < D0);
#pragma unroll
            for (int kh = 0; kh < 3; ++kh) {
                int h2 = 2 * ho - 1 + kh;
                bool rvv = dv && (h2 >= 0 && h2 < H0);
                float a0 = 0.f, a1 = 0.f, a2 = 0.f, a3 = 0.f;   // w2 = 2wo-1
                float b0 = 0.f, b1 = 0.f, b2 = 0.f, b3 = 0.f;   // w2 = 2wo
                float c0 = 0.f, c1 = 0.f, c2 = 0.f, c3 = 0.f;   // w2 = 2wo+1
                if (rvv) {
                    size_t r2 = (size_t)((d2 * H0 + h2) * W0 + 2 * wo);
                    uint4 AB = *(const uint4*)(base + r2 * 4);   // 16B: voxels 2wo, 2wo+1
                    b0 = lo16(AB.x); b1 = hi16(AB.x); b2 = lo16(AB.y); b3 = hi16(AB.y);
                    c0 = lo16(AB.z); c1 = hi16(AB.z); c2 = lo16(AB.w); c3 = hi16(AB.w);
                    if (wo > 0) {
                        uint2 P = *(const uint2*)(base + (r2 - 1) * 4);
                        a0 = lo16(P.x); a1 = hi16(P.x); a2 = lo16(P.y); a3 = hi16(P.y);
                    }
                }
                const float* wk = wg + kd * 9 + kh * 3;
#pragma unroll
                for (int m = 0; m < 4; ++m) {
                    const float* wm = wk + m * 324;
                    acc[m] += a0 * wm[0]  + b0 * wm[1]  + c0 * wm[2]
                            + a1 * wm[27] + b1 * wm[28] + c1 * wm[29]
                            + a2 * wm[54] + b2 * wm[55] + c2 * wm[56]
                            + a3 * wm[81] + b3 * wm[82] + c3 * wm[83];
                }
                if (kd >= 1 && kh >= 1) {        // pool = inner 2x2x2
                    mx0 = fmaxf(mx0, fmaxf(b0, c0));
                    mx1 = fmaxf(mx1, fmaxf(b1, c1));
                    mx2 = fmaxf(mx2, fmaxf(b2, c2));
                    mx3 = fmaxf(mx3, fmaxf(b3, c3));
                }
            }
        }
        *(float4*)(xo + 4 + 4 * g) = make_float4(fmaxf(mx0, 0.f), fmaxf(mx1, 0.f),
                                                 fmaxf(mx2, 0.f), fmaxf(mx3, 0.f));
    }
    *(float4*)(xo) = make_float4(fmaxf(acc[0], 0.f), fmaxf(acc[1], 0.f),
                                 fmaxf(acc[2], 0.f), fmaxf(acc[3], 0.f));
}

// ============================================================
// pw 16->4: x1 interleaved [N1][16] -> y0 interleaved [N1][4], relu
// ============================================================
__global__ void __launch_bounds__(256) kz_pw16to4i(const float* __restrict__ in,
                                                   const float* __restrict__ w,
                                                   float* __restrict__ out) {
    __shared__ float wl[64];
    if (threadIdx.x < 64) wl[threadIdx.x] = w[threadIdx.x];
    __syncthreads();
    int o = blockIdx.x * 256 + threadIdx.x;   // exact
    const float* ip = in + (size_t)o * 16;
    float4 A = *(const float4*)(ip);
    float4 B = *(const float4*)(ip + 4);
    float4 C = *(const float4*)(ip + 8);
    float4 D = *(const float4*)(ip + 12);
    float r[4];
#pragma unroll
    for (int m = 0; m < 4; ++m) {
        const float* wm = wl + m * 16;
        r[m] = A.x * wm[0] + A.y * wm[1] + A.z * wm[2] + A.w * wm[3]
             + B.x * wm[4] + B.y * wm[5] + B.z * wm[6] + B.w * wm[7]
             + C.x * wm[8] + C.y * wm[9] + C.z * wm[10] + C.w * wm[11]
             + D.x * wm[12] + D.y * wm[13] + D.z * wm[14] + D.w * wm[15];
    }
    *(float4*)(out + (size_t)o * 4) = make_float4(fmaxf(r[0], 0.f), fmaxf(r[1], 0.f),
                                                  fmaxf(r[2], 0.f), fmaxf(r[3], 0.f));
}

// ============================================================
// bconv 4ch interleaved [N1][4]: kernel (KD,KH,KW), bias, NADD residuals, relu
// ============================================================
template <int KD, int KH, int KW, int NADD>
__global__ void __launch_bounds__(256) kz_bconv4i(const float* __restrict__ in,
                                                  const float* __restrict__ w,
                                                  const float* __restrict__ b,
                                                  const float* __restrict__ add1,
                                                  const float* __restrict__ add2,
                                                  float* __restrict__ out) {
    constexpr int S = KD * KH * KW;
    __shared__ float wl[16 * S];
    __shared__ float bl[4];
    for (int t = threadIdx.x; t < 16 * S; t += 256) wl[t] = w[t];
    if (threadIdx.x < 4) bl[threadIdx.x] = b[threadIdx.x];
    __syncthreads();
    int o = blockIdx.x * 256 + threadIdx.x;   // exact: N1/256
    int wo = o % W1;
    int t  = o / W1;
    int ho = t % H1;
    int d0 = t / H1;
    float a0 = bl[0], a1 = bl[1], a2 = bl[2], a3 = bl[3];
#pragma unroll
    for (int kd = 0; kd < KD; ++kd) {
        int d2 = d0 + kd - KD / 2;
        if (KD > 1 && (d2 < 0 || d2 >= D1)) continue;
#pragma unroll
        for (int kh = 0; kh < KH; ++kh) {
            int h2 = ho + kh - KH / 2;
            if (KH > 1 && (h2 < 0 || h2 >= H1)) continue;
#pragma unroll
            for (int kw = 0; kw < KW; ++kw) {
                int w2 = wo + kw - KW / 2;
                if (KW > 1 && (w2 < 0 || w2 >= W1)) continue;
                float4 v = *(const float4*)(in + (size_t)((d2 * H1 + h2) * W1 + w2) * 4);
                int tap = (kd * KH + kh) * KW + kw;
                const float* wt = wl + tap;
                a0 += v.x * wt[0 * S] + v.y * wt[1 * S] + v.z * wt[2 * S] + v.w * wt[3 * S];
                a1 += v.x * wt[4 * S] + v.y * wt[5 * S] + v.z * wt[6 * S] + v.w * wt[7 * S];
                a2 += v.x * wt[8 * S] + v.y * wt[9 * S] + v.z * wt[10 * S] + v.w * wt[11 * S];
                a3 += v.x * wt[12 * S] + v.y * wt[13 * S] + v.z * wt[14 * S] + v.w * wt[15 * S];
            }
        }
    }
    if (NADD >= 1) {
        float4 r1 = *(const float4*)(add1 + (size_t)o * 4);
        a0 += r1.x; a1 += r1.y; a2 += r1.z; a3 += r1.w;
    }
    if (NADD >= 2) {
        float4 r2 = *(const float4*)(add2 + (size_t)o * 4);
        a0 += r2.x; a1 += r2.y; a2 += r2.z; a3 += r2.w;
    }
    *(float4*)(out + (size_t)o * 4) = make_float4(fmaxf(a0, 0.f), fmaxf(a1, 0.f),
                                                  fmaxf(a2, 0.f), fmaxf(a3, 0.f));
}

// ============================================================
// pw 4->16 + residual(x1 interleaved) + relu -> x1b PLANAR [16][N1]
// ============================================================
__global__ void __launch_bounds__(256) kz_pw4to16(const float* __restrict__ in,
                                                  const float* __restrict__ w,
                                                  const float* __restrict__ resi,
                                                  float* __restrict__ out) {
    __shared__ float wl[64];
    if (threadIdx.x < 64) wl[threadIdx.x] = w[threadIdx.x];
    __syncthreads();
    int o = blockIdx.x * 256 + threadIdx.x;   // exact
    float4 v = *(const float4*)(in + (size_t)o * 4);
    const float* rp = resi + (size_t)o * 16;
    float4 R0 = *(const float4*)(rp);
    float4 R1 = *(const float4*)(rp + 4);
    float4 R2 = *(const float4*)(rp + 8);
    float4 R3 = *(const float4*)(rp + 12);
    float rr[16] = {R0.x, R0.y, R0.z, R0.w, R1.x, R1.y, R1.z, R1.w,
                    R2.x, R2.y, R2.z, R2.w, R3.x, R3.y, R3.z, R3.w};
#pragma unroll
    for (int m = 0; m < 16; ++m) {
        const float* wm = wl + m * 4;
        float r = v.x * wm[0] + v.y * wm[1] + v.z * wm[2] + v.w * wm[3] + rr[m];
        out[(size_t)m * N1 + o] = fmaxf(r, 0.f);
    }
}

// ============================================================
// Downsample 2: conv3d 16->16 (k3,s2,p1) ++ maxpool2 of 16ch, relu (planar f32)
// ============================================================
__global__ void __launch_bounds__(256) kz_ds2(const float* __restrict__ in,
                                              const float* __restrict__ w,
                                              float* __restrict__ out) {
    __shared__ float wl[16 * 16 * 27];
    for (int t = threadIdx.x; t < 16 * 16 * 27; t += 256) wl[t] = w[t];
    __syncthreads();
    int o = blockIdx.x * 256 + threadIdx.x;
    if (o >= N2) return;
    int wo = o % W2;
    int t  = o / W2;
    int ho = t % H2;
    int d0 = t / H2;
    float acc[16];
#pragma unroll
    for (int m = 0; m < 16; ++m) acc[m] = 0.f;
#pragma unroll 1
    for (int ci = 0; ci < 16; ++ci) {
        const float* base = in + ci * N1;
        const float* wci = wl + ci * 27;
        float mx = -1e30f;
#pragma unroll 1
        for (int kd = 0; kd < 3; ++kd) {
            int d2 = 2 * d0 - 1 + kd;
            bool dv = (d2 >= 0 && d2 < D1);
#pragma unroll
            for (int kh = 0; kh < 3; ++kh) {
                int h2 = 2 * ho - 1 + kh;
                bool rvv = dv && (h2 >= 0 && h2 < H1);
                float vm1 = 0.f, v0 = 0.f, v1 = 0.f;
                if (rvv) {
                    int r2 = (d2 * H1 + h2) * W1 + 2 * wo;
                    float2 pb = *(const float2*)(base + r2);
                    v0 = pb.x; v1 = pb.y;
                    if (wo > 0) {
                        float2 pa = *(const float2*)(base + r2 - 2);
                        vm1 = pa.y;
                    }
                }
                const float* wk = wci + kd * 9 + kh * 3;
#pragma unroll
                for (int m = 0; m < 16; ++m)
                    acc[m] += vm1 * wk[m * 432] + v0 * wk[m * 432 + 1] + v1 * wk[m * 432 + 2];
                if (kd >= 1 && kh >= 1) mx = fmaxf(mx, fmaxf(v0, v1));
            }
        }
        out[(16 + ci) * N2 + o] = fmaxf(mx, 0.f);
    }
#pragma unroll
    for (int m = 0; m < 16; ++m) out[m * N2 + o] = fmaxf(acc[m], 0.f);
}

// ============================================================
// pw 32->8: x2 planar [32][N2] -> z0 interleaved [N2][8], relu
// ============================================================
__global__ void __launch_bounds__(256) kz_pw32to8i(const float* __restrict__ in,
                                                   const float* __restrict__ w,
                                                   float* __restrict__ out) {
    __shared__ float wl[256];
    if (threadIdx.x < 256) wl[threadIdx.x] = w[threadIdx.x];
    __syncthreads();
    int o = blockIdx.x * 256 + threadIdx.x;
    if (o >= N2) return;
    float acc[8];
#pragma unroll
    for (int m = 0; m < 8; ++m) acc[m] = 0.f;
#pragma unroll
    for (int ci = 0; ci < 32; ++ci) {
        float v = in[(size_t)ci * N2 + o];
#pragma unroll
        for (int m = 0; m < 8; ++m) acc[m] += v * wl[m * 32 + ci];
    }
    float* op = out + (size_t)o * 8;
    *(float4*)(op)     = make_float4(fmaxf(acc[0], 0.f), fmaxf(acc[1], 0.f),
                                     fmaxf(acc[2], 0.f), fmaxf(acc[3], 0.f));
    *(float4*)(op + 4) = make_float4(fmaxf(acc[4], 0.f), fmaxf(acc[5], 0.f),
                                     fmaxf(acc[6], 0.f), fmaxf(acc[7], 0.f));
}

// ============================================================
// bconv 8ch interleaved [N2][8]: kernel (KD,KH,KW), bias, NADD residuals, relu
// ============================================================
template <int KD, int KH, int KW, int NADD>
__global__ void __launch_bounds__(256) kz_bconv8i(const float* __restrict__ in,
                                                  const float* __restrict__ w,
                                                  const float* __restrict__ b,
                                                  const float* __restrict__ add1,
                                                  const float* __restrict__ add2,
                                                  float* __restrict__ out) {
    constexpr int S = KD * KH * KW;
    __shared__ float wl[64 * S];
    __shared__ float bl[8];
    for (int t = threadIdx.x; t < 64 * S; t += 256) wl[t] = w[t];
    if (threadIdx.x < 8) bl[threadIdx.x] = b[threadIdx.x];
    __syncthreads();
    int o = blockIdx.x * 256 + threadIdx.x;
    if (o >= N2) return;
    int wo = o % W2;
    int t  = o / W2;
    int ho = t % H2;
    int d0 = t / H2;
    float acc[8];
#pragma unroll
    for (int m = 0; m < 8; ++m) acc[m] = bl[m];
#pragma unroll
    for (int kd = 0; kd < KD; ++kd) {
        int d2 = d0 + kd - KD / 2;
        if (KD > 1 && (d2 < 0 || d2 >= D2)) continue;
#pragma unroll
        for (int kh = 0; kh < KH; ++kh) {
            int h2 = ho + kh - KH / 2;
            if (KH > 1 && (h2 < 0 || h2 >= H2)) continue;
#pragma unroll
            for (int kw = 0; kw < KW; ++kw) {
                int w2 = wo + kw - KW / 2;
                if (KW > 1 && (w2 < 0 || w2 >= W2)) continue;
                const float* vp = in + (size_t)((d2 * H2 + h2) * W2 + w2) * 8;
                float4 v0 = *(const float4*)(vp);
                float4 v1 = *(const float4*)(vp + 4);
                int tap = (kd * KH + kh) * KW + kw;
                const float* wt = wl + tap;
#pragma unroll
                for (int m = 0; m < 8; ++m) {
                    const float* wm = wt + m * 8 * S;
                    acc[m] += v0.x * wm[0] + v0.y * wm[S] + v0.z * wm[2 * S] + v0.w * wm[3 * S]
                            + v1.x * wm[4 * S] + v1.y * wm[5 * S] + v1.z * wm[6 * S] + v1.w * wm[7 * S];
                }
            }
        }
    }
    if (NADD >= 1) {
        const float* ap = add1 + (size_t)o * 8;
        float4 r0 = *(const float4*)(ap), r1 = *(const float4*)(ap + 4);
        acc[0] += r0.x; acc[1] += r0.y; acc[2] += r0.z; acc[3] += r0.w;
        acc[4] += r1.x; acc[5] += r1.y; acc[6] += r1.z; acc[7] += r1.w;
    }
    if (NADD >= 2) {
        const float* ap = add2 + (size_t)o * 8;
        float4 r0 = *(const float4*)(ap), r1 = *(const float4*)(ap + 4);
        acc[0] += r0.x; acc[1] += r0.y; acc[2] += r0.z; acc[3] += r0.w;
        acc[4] += r1.x; acc[5] += r1.y; acc[6] += r1.z; acc[7] += r1.w;
    }
    float* op = out + (size_t)o * 8;
    *(float4*)(op)     = make_float4(fmaxf(acc[0], 0.f), fmaxf(acc[1], 0.f),
                                     fmaxf(acc[2], 0.f), fmaxf(acc[3], 0.f));
    *(float4*)(op + 4) = make_float4(fmaxf(acc[4], 0.f), fmaxf(acc[5], 0.f),
                                     fmaxf(acc[6], 0.f), fmaxf(acc[7], 0.f));
}

// ============================================================
// pw 8->32 + residual(x2 planar) + relu -> d_out planar [32][N2]
// ============================================================
__global__ void __launch_bounds__(256) kz_pw8to32(const float* __restrict__ in,
                                                  const float* __restrict__ w,
                                                  const float* __restrict__ resp,
                                                  float* __restrict__ out) {
    __shared__ float wl[256];
    if (threadIdx.x < 256) wl[threadIdx.x] = w[threadIdx.x];
    __syncthreads();
    int o = blockIdx.x * 256 + threadIdx.x;
    if (o >= N2) return;
    const float* ip = in + (size_t)o * 8;
    float4 v0 = *(const float4*)(ip);
    float4 v1 = *(const float4*)(ip + 4);
#pragma unroll
    for (int m = 0; m < 32; ++m) {
        const float* wm = wl + m * 8;
        float r = v0.x * wm[0] + v0.y * wm[1] + v0.z * wm[2] + v0.w * wm[3]
                + v1.x * wm[4] + v1.y * wm[5] + v1.z * wm[6] + v1.w * wm[7];
        r += resp[(size_t)m * N2 + o];
        out[(size_t)m * N2 + o] = fmaxf(r, 0.f);
    }
}

// ============================================================
extern "C" void kernel_launch(void* const* d_in, const int* in_sizes, int n_in,
                              void* d_out, int out_size, void* d_ws, size_t ws_size,
                              hipStream_t stream) {
    const float* feat   = (const float*)d_in[0];
    const int*   depth  = (const int*)d_in[1];
    const float* w_ds1  = (const float*)d_in[2];
    const float* b1_win = (const float*)d_in[3];
    const float* b1w133 = (const float*)d_in[4];
    const float* b1b133 = (const float*)d_in[5];
    const float* b1w331 = (const float*)d_in[6];
    const float* b1b331 = (const float*)d_in[7];
    const float* b1w313 = (const float*)d_in[8];
    const float* b1b313 = (const float*)d_in[9];
    const float* b1wout = (const float*)d_in[10];
    const float* w_ds2  = (const float*)d_in[11];
    const float* b2_win = (const float*)d_in[12];
    const float* b2w133 = (const float*)d_in[13];
    const float* b2b133 = (const float*)d_in[14];
    const float* b2w331 = (const float*)d_in[15];
    const float* b2b331 = (const float*)d_in[16];
    const float* b2w313 = (const float*)d_in[17];
    const float* b2b313 = (const float*)d_in[18];
    const float* b2wout = (const float*)d_in[19];

    char* base = (char*)d_ws;

    // --- Region layout (time-shared; peak = 265.4 MB, proven safe; R9 plan) ---
    u16* segu = (u16*)base;                               // [0, 199): 3 groups [V][4], filled in-place
    unsigned* winner = (unsigned*)(base + SEG_BYTES);     // [199, 232)
    u16*      tmpu   = (u16*)(base + SEG_BYTES);          // [199, 265) after winner dies
    float*    x1i    = (float*)(base + SEG_BYTES);        // [N1][16] f32, [199, 265) after tmpu dies
    float* y0i = (float*)base;                            // [N1][4] each, after segu dies
    float* y1i = y0i + 4 * N1;
    float* y2i = y1i + 4 * N1;
    float* y3i = y2i + 4 * N1;                            // y* occupy [0, 66.35)
    float* x1b = (float*)(base + GRP_BYTES);              // planar [16][N1], [66.35, 132.7)
    float* x2  = (float*)base;                            // planar [32][N2], after y dead
    float* z0i = x2 + 32 * N2;                            // [N2][8] each
    float* z1i = z0i + 8 * N2;
    float* z2i = z1i + 8 * N2;
    float* z3i = z2i + 8 * N2;                            // ends ~33 MB < x1b start

    float* out = (float*)d_out;   // reference output dtype is float32

    // 1. zero volume + winner (contiguous)
    kz_zero16<<<ZCHUNKS / 256, 256, 0, stream>>>((uint4*)base, ZCHUNKS);

    // 2. deterministic last-write-wins scatter
    kz_scatter_win  <<<NPIX / 256, 256, 0, stream>>>(depth, winner);
    kz_scatter_write<<<NPIX / 256, 256, 0, stream>>>(depth, winner, feat, segu);

    // 3. avg-pool hole-fill, 2-pass per group, in-place (R9-proven)
    for (int g = 0; g < 3; ++g) {
        u16* gb = segu + (size_t)g * GRP_U16;
        kz_sumwI<<<(V / 2) / 256, 256, 0, stream>>>(gb, tmpu);
        kz_fillI<<<(V / 2) / 256, 256, 0, stream>>>(gb, tmpu);
    }

    // 4. downsample 1 -> x1 interleaved [N1][16]
    kz_ds1<<<N1 / 256, 256, 0, stream>>>(segu, w_ds1, x1i);

    // 5. bottleneck 1, channel-interleaved [N1][4]
    kz_pw16to4i<<<N1 / 256, 256, 0, stream>>>(x1i, b1_win, y0i);
    kz_bconv4i<1, 3, 3, 0><<<N1 / 256, 256, 0, stream>>>(y0i, b1w133, b1b133, nullptr, nullptr, y1i);
    kz_bconv4i<3, 3, 1, 1><<<N1 / 256, 256, 0, stream>>>(y1i, b1w331, b1b331, y1i, nullptr, y2i);
    kz_bconv4i<3, 1, 3, 2><<<N1 / 256, 256, 0, stream>>>(y2i, b1w313, b1b313, y2i, y1i, y3i);
    kz_pw4to16<<<N1 / 256, 256, 0, stream>>>(y3i, b1wout, x1i, x1b);

    // 6. downsample 2 (planar) -> x2 planar [32][N2]
    kz_ds2<<<(N2 + 255) / 256, 256, 0, stream>>>(x1b, w_ds2, x2);

    // 7. bottleneck 2, channel-interleaved [N2][8] -> f32 d_out
    kz_pw32to8i<<<(N2 + 255) / 256, 256, 0, stream>>>(x2, b2_win, z0i);
    kz_bconv8i<1, 3, 3, 0><<<(N2 + 255) / 256, 256, 0, stream>>>(z0i, b2w133, b2b133, nullptr, nullptr, z1i);
    kz_bconv8i<3, 3, 1, 1><<<(N2 + 255) / 256, 256, 0, stream>>>(z1i, b2w331, b2b331, z1i, nullptr, z2i);
    kz_bconv8i<3, 1, 3, 2><<<(N2 + 255) / 256, 256, 0, stream>>>(z2i, b2w313, b2b313, z2i, z1i, z3i);
    kz_pw8to32<<<(N2 + 255) / 256, 256, 0, stream>>>(z3i, b2wout, x2, out);

    (void)in_sizes; (void)n_in; (void)out_size; (void)ws_size;
}

// Round 12
// 822.382 us; speedup vs baseline: 1.1497x; 1.0142x over previous
//
#include <hip/hip_runtime.h>
#include <hip/hip_bf16.h>

typedef __hip_bfloat16 bf16;
typedef unsigned short u16;

// bf16 bits -> f32 (exact)
static __device__ __forceinline__ float lo16(unsigned u) { return __uint_as_float(u << 16); }
static __device__ __forceinline__ float hi16(unsigned u) { return __uint_as_float(u & 0xFFFF0000u); }
// f32 -> bf16 bits, round-to-nearest-even (no NaNs in this pipeline)
static __device__ __forceinline__ unsigned f2u(float x) {
    unsigned u = __float_as_uint(x);
    return (u + 0x7FFFu + ((u >> 16) & 1u)) >> 16;
}
static __device__ __forceinline__ unsigned pack2(float a, float b) {
    return f2u(a) | (f2u(b) << 16);
}

// ---- problem constants ----
constexpr int D0 = 240, H0 = 144, W0 = 240;
constexpr int V  = D0 * H0 * W0;          // 8,294,400 voxels
constexpr int NPIX = 480 * 640;           // 307,200 pixels
constexpr int D1 = 120, H1 = 72, W1 = 120;
constexpr int N1 = D1 * H1 * W1;          // 1,036,800
constexpr int D2 = 60, H2 = 36, W2 = 60;
constexpr int N2 = D2 * H2 * W2;          // 129,600

// Volume layout: 3 groups x [V][4] bf16 (channel ci = 4*g + c)
constexpr size_t GRP_U16  = (size_t)V * 4;                    // u16 per group
constexpr size_t GRP_BYTES = GRP_U16 * sizeof(u16);           // 66,355,200
constexpr size_t SEG_BYTES = 3 * GRP_BYTES;                   // 199,065,600
constexpr size_t WIN_BYTES = (size_t)V * sizeof(unsigned);    // 33,177,600
constexpr int ZCHUNKS = (int)((SEG_BYTES + WIN_BYTES) / 16);  // 14,515,200 uint4
// Peak ws: SEG_BYTES + GRP_BYTES = 265,420,800 bytes — proven safe.

// ============================================================
// Zero-fill (uint4)
// ============================================================
__global__ void __launch_bounds__(256) kz_zero16(uint4* __restrict__ p, int nchunks) {
    int i = blockIdx.x * 256 + threadIdx.x;
    if (i >= nchunks) return;
    p[i] = make_uint4(0u, 0u, 0u, 0u);
}

// ============================================================
// Scatter: last-write-wins via winner = max(pixel_index+1)
// ============================================================
__global__ void __launch_bounds__(256) kz_scatter_win(const int* __restrict__ depth,
                                                      unsigned* __restrict__ winner) {
    int p = blockIdx.x * 256 + threadIdx.x;
    if (p >= NPIX) return;
    int d = depth[p];
    if (d > 0 && d < V) atomicMax(&winner[d], (unsigned)(p + 1));
}

__global__ void __launch_bounds__(256) kz_scatter_write(const int* __restrict__ depth,
                                                        const unsigned* __restrict__ winner,
                                                        const float* __restrict__ feat,
                                                        u16* __restrict__ seg) {
    int p = blockIdx.x * 256 + threadIdx.x;
    if (p >= NPIX) return;
    int d = depth[p];
    if (d > 0 && d < V && winner[d] == (unsigned)(p + 1)) {
#pragma unroll
        for (int g = 0; g < 3; ++g) {
            uint2 val;
            val.x = pack2(feat[(4 * g + 0) * NPIX + p], feat[(4 * g + 1) * NPIX + p]);
            val.y = pack2(feat[(4 * g + 2) * NPIX + p], feat[(4 * g + 3) * NPIX + p]);
            *(uint2*)(seg + g * GRP_U16 + (size_t)d * 4) = val;
        }
    }
}

// ============================================================
// Fill pass A (one group [V][4]): 3-tap W sums -> bf16 tmp (R9-proven)
// ============================================================
__global__ void __launch_bounds__(256) kz_sumwI(const u16* __restrict__ sb,
                                                u16* __restrict__ tb) {
    int r = blockIdx.x * 256 + threadIdx.x;      // grid exact: V/2/256
    int i = 2 * r;
    int w = i % W0;
    uint4 X = *(const uint4*)(sb + (size_t)i * 4);
    float x0[4] = {lo16(X.x), hi16(X.x), lo16(X.y), hi16(X.y)};
    float x1[4] = {lo16(X.z), hi16(X.z), lo16(X.w), hi16(X.w)};
    float l[4] = {0.f, 0.f, 0.f, 0.f}, rr[4] = {0.f, 0.f, 0.f, 0.f};
    if (w > 0) {
        uint2 L = *(const uint2*)(sb + (size_t)(i - 1) * 4);
        l[0] = lo16(L.x); l[1] = hi16(L.x); l[2] = lo16(L.y); l[3] = hi16(L.y);
    }
    if (w < 238) {
        uint2 R = *(const uint2*)(sb + (size_t)(i + 2) * 4);
        rr[0] = lo16(R.x); rr[1] = hi16(R.x); rr[2] = lo16(R.y); rr[3] = hi16(R.y);
    }
    uint4 O;
    O.x = pack2(l[0] + x0[0] + x1[0], l[1] + x0[1] + x1[1]);
    O.y = pack2(l[2] + x0[2] + x1[2], l[3] + x0[3] + x1[3]);
    O.z = pack2(x0[0] + x1[0] + rr[0], x0[1] + x1[1] + rr[1]);
    O.w = pack2(x0[2] + x1[2] + rr[2], x0[3] + x1[3] + rr[3]);
    *(uint4*)(tb + (size_t)i * 4) = O;
}

// ============================================================
// Fill pass B (one group, IN-PLACE): 9-tap (d,h) sum, /27, where raw==0
// (R9-proven)
// ============================================================
__global__ void __launch_bounds__(256) kz_fillI(u16* __restrict__ rb,
                                                const u16* __restrict__ tb) {
    int r = blockIdx.x * 256 + threadIdx.x;
    int i = 2 * r;
    uint4 R = *(const uint4*)(rb + (size_t)i * 4);
    bool z[8];
    z[0] = (R.x & 0x7FFFu) == 0;          z[1] = ((R.x >> 16) & 0x7FFFu) == 0;
    z[2] = (R.y & 0x7FFFu) == 0;          z[3] = ((R.y >> 16) & 0x7FFFu) == 0;
    z[4] = (R.z & 0x7FFFu) == 0;          z[5] = ((R.z >> 16) & 0x7FFFu) == 0;
    z[6] = (R.w & 0x7FFFu) == 0;          z[7] = ((R.w >> 16) & 0x7FFFu) == 0;
    if (!(z[0] | z[1] | z[2] | z[3] | z[4] | z[5] | z[6] | z[7])) return;
    int w = i % W0;
    int t = i / W0;
    int h = t % H0;
    int d = t / H0;
    float s[8] = {0.f, 0.f, 0.f, 0.f, 0.f, 0.f, 0.f, 0.f};
#pragma unroll
    for (int dd = -1; dd <= 1; ++dd) {
        int d2 = d + dd;
        if (d2 < 0 || d2 >= D0) continue;
#pragma unroll
        for (int dh = -1; dh <= 1; ++dh) {
            int h2 = h + dh;
            if (h2 < 0 || h2 >= H0) continue;
            uint4 T = *(const uint4*)(tb + (size_t)((d2 * H0 + h2) * W0 + w) * 4);
            s[0] += lo16(T.x); s[1] += hi16(T.x); s[2] += lo16(T.y); s[3] += hi16(T.y);
            s[4] += lo16(T.z); s[5] += hi16(T.z); s[6] += lo16(T.w); s[7] += hi16(T.w);
        }
    }
    constexpr float inv27 = 1.0f / 27.0f;
    uint4 O;
    O.x = (z[0] ? f2u(s[0] * inv27) : (R.x & 0xFFFFu)) | ((z[1] ? f2u(s[1] * inv27) : (R.x >> 16)) << 16);
    O.y = (z[2] ? f2u(s[2] * inv27) : (R.y & 0xFFFFu)) | ((z[3] ? f2u(s[3] * inv27) : (R.y >> 16)) << 16);
    O.z = (z[4] ? f2u(s[4] * inv27) : (R.z & 0xFFFFu)) | ((z[5] ? f2u(s[5] * inv27) : (R.z >> 16)) << 16);
    O.w = (z[6] ? f2u(s[6] * inv27) : (R.w & 0xFFFFu)) | ((z[7] ? f2u(s[7] * inv27) : (R.w >> 16)) << 16);
    *(uint4*)(rb + (size_t)i * 4) = O;
}

// ============================================================
// Downsample 1: conv 12->4 (k3,s2,p1) ++ maxpool2, relu.
// Pool channels stashed in LDS (per-thread slots, no barrier), all 16 x1
// values stored back-to-back at the end (fixes 2x write amplification).
// ============================================================
__global__ void __launch_bounds__(256) kz_ds1(const u16* __restrict__ seg,
                                              const float* __restrict__ w,
                                              float* __restrict__ x1i) {
    __shared__ float wl[4 * 12 * 27];
    __shared__ float pool[12 * 256];   // [plane p=4g+c][tid], stride-1 lanes: conflict-free
    for (int t = threadIdx.x; t < 4 * 12 * 27; t += 256) wl[t] = w[t];
    __syncthreads();
    int tid = threadIdx.x;
    int o = blockIdx.x * 256 + tid;    // grid exact: N1/256 = 4050
    int wo = o % W1;
    int t  = o / W1;
    int ho = t % H1;
    int d0 = t / H1;
    float acc[4] = {0.f, 0.f, 0.f, 0.f};
#pragma unroll 1
    for (int g = 0; g < 3; ++g) {
        const u16* base = seg + (size_t)g * GRP_U16;
        const float* wg = wl + (4 * g) * 27;
        float mx0 = -1e30f, mx1 = -1e30f, mx2 = -1e30f, mx3 = -1e30f;
#pragma unroll 1
        for (int kd = 0; kd < 3; ++kd) {
            int d2 = 2 * d0 - 1 + kd;
            bool dv = (d2 >= 0 && d2 < D0);
#pragma unroll
            for (int kh = 0; kh < 3; ++kh) {
                int h2 = 2 * ho - 1 + kh;
                bool rvv = dv && (h2 >= 0 && h2 < H0);
                float a0 = 0.f, a1 = 0.f, a2 = 0.f, a3 = 0.f;   // w2 = 2wo-1
                float b0 = 0.f, b1 = 0.f, b2 = 0.f, b3 = 0.f;   // w2 = 2wo
                float c0 = 0.f, c1 = 0.f, c2 = 0.f, c3 = 0.f;   // w2 = 2wo+1
                if (rvv) {
                    size_t r2 = (size_t)((d2 * H0 + h2) * W0 + 2 * wo);
                    uint4 AB = *(const uint4*)(base + r2 * 4);
                    b0 = lo16(AB.x); b1 = hi16(AB.x); b2 = lo16(AB.y); b3 = hi16(AB.y);
                    c0 = lo16(AB.z); c1 = hi16(AB.z); c2 = lo16(AB.w); c3 = hi16(AB.w);
                    if (wo > 0) {
                        uint2 P = *(const uint2*)(base + (r2 - 1) * 4);
                        a0 = lo16(P.x); a1 = hi16(P.x); a2 = lo16(P.y); a3 = hi16(P.y);
                    }
                }
                const float* wk = wg + kd * 9 + kh * 3;
#pragma unroll
                for (int m = 0; m < 4; ++m) {
                    const float* wm = wk + m * 324;
                    acc[m] += a0 * wm[0]  + b0 * wm[1]  + c0 * wm[2]
                            + a1 * wm[27] + b1 * wm[28] + c1 * wm[29]
                            + a2 * wm[54] + b2 * wm[55] + c2 * wm[56]
                            + a3 * wm[81] + b3 * wm[82] + c3 * wm[83];
                }
                if (kd >= 1 && kh >= 1) {        // pool = inner 2x2x2
                    mx0 = fmaxf(mx0, fmaxf(b0, c0));
                    mx1 = fmaxf(mx1, fmaxf(b1, c1));
                    mx2 = fmaxf(mx2, fmaxf(b2, c2));
                    mx3 = fmaxf(mx3, fmaxf(b3, c3));
                }
            }
        }
        pool[(4 * g + 0) * 256 + tid] = fmaxf(mx0, 0.f);
        pool[(4 * g + 1) * 256 + tid] = fmaxf(mx1, 0.f);
        pool[(4 * g + 2) * 256 + tid] = fmaxf(mx2, 0.f);
        pool[(4 * g + 3) * 256 + tid] = fmaxf(mx3, 0.f);
    }
    float* xo = x1i + (size_t)o * 16;
    float4 q0 = make_float4(fmaxf(acc[0], 0.f), fmaxf(acc[1], 0.f),
                            fmaxf(acc[2], 0.f), fmaxf(acc[3], 0.f));
    float4 q1 = make_float4(pool[0 * 256 + tid], pool[1 * 256 + tid],
                            pool[2 * 256 + tid], pool[3 * 256 + tid]);
    float4 q2 = make_float4(pool[4 * 256 + tid], pool[5 * 256 + tid],
                            pool[6 * 256 + tid], pool[7 * 256 + tid]);
    float4 q3 = make_float4(pool[8 * 256 + tid], pool[9 * 256 + tid],
                            pool[10 * 256 + tid], pool[11 * 256 + tid]);
    *(float4*)(xo)      = q0;
    *(float4*)(xo + 4)  = q1;
    *(float4*)(xo + 8)  = q2;
    *(float4*)(xo + 12) = q3;
}

// ============================================================
// pw 16->4: x1 interleaved [N1][16] -> y0 interleaved [N1][4], relu
// ============================================================
__global__ void __launch_bounds__(256) kz_pw16to4i(const float* __restrict__ in,
                                                   const float* __restrict__ w,
                                                   float* __restrict__ out) {
    __shared__ float wl[64];
    if (threadIdx.x < 64) wl[threadIdx.x] = w[threadIdx.x];
    __syncthreads();
    int o = blockIdx.x * 256 + threadIdx.x;   // exact
    const float* ip = in + (size_t)o * 16;
    float4 A = *(const float4*)(ip);
    float4 B = *(const float4*)(ip + 4);
    float4 C = *(const float4*)(ip + 8);
    float4 D = *(const float4*)(ip + 12);
    float r[4];
#pragma unroll
    for (int m = 0; m < 4; ++m) {
        const float* wm = wl + m * 16;
        r[m] = A.x * wm[0] + A.y * wm[1] + A.z * wm[2] + A.w * wm[3]
             + B.x * wm[4] + B.y * wm[5] + B.z * wm[6] + B.w * wm[7]
             + C.x * wm[8] + C.y * wm[9] + C.z * wm[10] + C.w * wm[11]
             + D.x * wm[12] + D.y * wm[13] + D.z * wm[14] + D.w * wm[15];
    }
    *(float4*)(out + (size_t)o * 4) = make_float4(fmaxf(r[0], 0.f), fmaxf(r[1], 0.f),
                                                  fmaxf(r[2], 0.f), fmaxf(r[3], 0.f));
}

// ============================================================
// bconv 4ch interleaved [N1][4]: (KD,KH,KW), bias, NADD residuals, relu
// ============================================================
template <int KD, int KH, int KW, int NADD>
__global__ void __launch_bounds__(256) kz_bconv4i(const float* __restrict__ in,
                                                  const float* __restrict__ w,
                                                  const float* __restrict__ b,
                                                  const float* __restrict__ add1,
                                                  const float* __restrict__ add2,
                                                  float* __restrict__ out) {
    constexpr int S = KD * KH * KW;
    __shared__ float wl[16 * S];
    __shared__ float bl[4];
    for (int t = threadIdx.x; t < 16 * S; t += 256) wl[t] = w[t];
    if (threadIdx.x < 4) bl[threadIdx.x] = b[threadIdx.x];
    __syncthreads();
    int o = blockIdx.x * 256 + threadIdx.x;   // exact: N1/256
    int wo = o % W1;
    int t  = o / W1;
    int ho = t % H1;
    int d0 = t / H1;
    float a0 = bl[0], a1 = bl[1], a2 = bl[2], a3 = bl[3];
#pragma unroll
    for (int kd = 0; kd < KD; ++kd) {
        int d2 = d0 + kd - KD / 2;
        if (KD > 1 && (d2 < 0 || d2 >= D1)) continue;
#pragma unroll
        for (int kh = 0; kh < KH; ++kh) {
            int h2 = ho + kh - KH / 2;
            if (KH > 1 && (h2 < 0 || h2 >= H1)) continue;
#pragma unroll
            for (int kw = 0; kw < KW; ++kw) {
                int w2 = wo + kw - KW / 2;
                if (KW > 1 && (w2 < 0 || w2 >= W1)) continue;
                float4 v = *(const float4*)(in + (size_t)((d2 * H1 + h2) * W1 + w2) * 4);
                int tap = (kd * KH + kh) * KW + kw;
                const float* wt = wl + tap;
                a0 += v.x * wt[0 * S] + v.y * wt[1 * S] + v.z * wt[2 * S] + v.w * wt[3 * S];
                a1 += v.x * wt[4 * S] + v.y * wt[5 * S] + v.z * wt[6 * S] + v.w * wt[7 * S];
                a2 += v.x * wt[8 * S] + v.y * wt[9 * S] + v.z * wt[10 * S] + v.w * wt[11 * S];
                a3 += v.x * wt[12 * S] + v.y * wt[13 * S] + v.z * wt[14 * S] + v.w * wt[15 * S];
            }
        }
    }
    if (NADD >= 1) {
        float4 r1 = *(const float4*)(add1 + (size_t)o * 4);
        a0 += r1.x; a1 += r1.y; a2 += r1.z; a3 += r1.w;
    }
    if (NADD >= 2) {
        float4 r2 = *(const float4*)(add2 + (size_t)o * 4);
        a0 += r2.x; a1 += r2.y; a2 += r2.z; a3 += r2.w;
    }
    *(float4*)(out + (size_t)o * 4) = make_float4(fmaxf(a0, 0.f), fmaxf(a1, 0.f),
                                                  fmaxf(a2, 0.f), fmaxf(a3, 0.f));
}

// ============================================================
// FUSED: bconv4 (3,1,3) + bias + 2 residuals + relu  ->  y3 (regs)
//        -> pw 4->16 + residual(x1i) + relu -> x1b PLANAR [16][N1]
// ============================================================
__global__ void __launch_bounds__(256) kz_bconv4i_pw(const float* __restrict__ in,
                                                     const float* __restrict__ w,
                                                     const float* __restrict__ b,
                                                     const float* __restrict__ add1,
                                                     const float* __restrict__ add2,
                                                     const float* __restrict__ wp,  // (16,4)
                                                     const float* __restrict__ x1i,
                                                     float* __restrict__ out) {
    constexpr int S = 9;   // 3*1*3
    __shared__ float wl[16 * S];
    __shared__ float bl[4];
    __shared__ float wpl[64];
    for (int t = threadIdx.x; t < 16 * S; t += 256) wl[t] = w[t];
    if (threadIdx.x < 4) bl[threadIdx.x] = b[threadIdx.x];
    if (threadIdx.x < 64) wpl[threadIdx.x] = wp[threadIdx.x];
    __syncthreads();
    int o = blockIdx.x * 256 + threadIdx.x;   // exact
    int wo = o % W1;
    int t  = o / W1;
    int ho = t % H1;
    int d0 = t / H1;
    float a0 = bl[0], a1 = bl[1], a2 = bl[2], a3 = bl[3];
#pragma unroll
    for (int kd = 0; kd < 3; ++kd) {
        int d2 = d0 + kd - 1;
        if (d2 < 0 || d2 >= D1) continue;
#pragma unroll
        for (int kw = 0; kw < 3; ++kw) {
            int w2 = wo + kw - 1;
            if (w2 < 0 || w2 >= W1) continue;
            float4 v = *(const float4*)(in + (size_t)((d2 * H1 + ho) * W1 + w2) * 4);
            int tap = kd * 3 + kw;
            const float* wt = wl + tap;
            a0 += v.x * wt[0 * S] + v.y * wt[1 * S] + v.z * wt[2 * S] + v.w * wt[3 * S];
            a1 += v.x * wt[4 * S] + v.y * wt[5 * S] + v.z * wt[6 * S] + v.w * wt[7 * S];
            a2 += v.x * wt[8 * S] + v.y * wt[9 * S] + v.z * wt[10 * S] + v.w * wt[11 * S];
            a3 += v.x * wt[12 * S] + v.y * wt[13 * S] + v.z * wt[14 * S] + v.w * wt[15 * S];
        }
    }
    float4 r1 = *(const float4*)(add1 + (size_t)o * 4);
    float4 r2 = *(const float4*)(add2 + (size_t)o * 4);
    float y0 = fmaxf(a0 + r1.x + r2.x, 0.f);
    float y1 = fmaxf(a1 + r1.y + r2.y, 0.f);
    float y2 = fmaxf(a2 + r1.z + r2.z, 0.f);
    float y3 = fmaxf(a3 + r1.w + r2.w, 0.f);
    const float* rp = x1i + (size_t)o * 16;
    float4 R0 = *(const float4*)(rp);
    float4 R1 = *(const float4*)(rp + 4);
    float4 R2 = *(const float4*)(rp + 8);
    float4 R3 = *(const float4*)(rp + 12);
    float rr[16] = {R0.x, R0.y, R0.z, R0.w, R1.x, R1.y, R1.z, R1.w,
                    R2.x, R2.y, R2.z, R2.w, R3.x, R3.y, R3.z, R3.w};
#pragma unroll
    for (int m = 0; m < 16; ++m) {
        const float* wm = wpl + m * 4;
        float r = y0 * wm[0] + y1 * wm[1] + y2 * wm[2] + y3 * wm[3] + rr[m];
        out[(size_t)m * N1 + o] = fmaxf(r, 0.f);
    }
}

// ============================================================
// FUSED Downsample 2 + pw 32->8: conv16->16(k3,s2,p1) ++ pool16, relu
// -> x2 planar [32][N2]  AND  z0 = relu(Wz . x2) interleaved [N2][8]
// ============================================================
__global__ void __launch_bounds__(256) kz_ds2f(const float* __restrict__ in,
                                               const float* __restrict__ w,
                                               const float* __restrict__ wz,  // (8,32)
                                               float* __restrict__ out,
                                               float* __restrict__ z0i) {
    __shared__ float wl[16 * 16 * 27];
    __shared__ float wzl[256];
    for (int t = threadIdx.x; t < 16 * 16 * 27; t += 256) wl[t] = w[t];
    if (threadIdx.x < 256) wzl[threadIdx.x] = wz[threadIdx.x];
    __syncthreads();
    int o = blockIdx.x * 256 + threadIdx.x;
    if (o >= N2) return;
    int wo = o % W2;
    int t  = o / W2;
    int ho = t % H2;
    int d0 = t / H2;
    float acc[16];
    float zacc[8];
#pragma unroll
    for (int m = 0; m < 16; ++m) acc[m] = 0.f;
#pragma unroll
    for (int m = 0; m < 8; ++m) zacc[m] = 0.f;
#pragma unroll 1
    for (int ci = 0; ci < 16; ++ci) {
        const float* base = in + ci * N1;
        const float* wci = wl + ci * 27;
        float mx = -1e30f;
#pragma unroll 1
        for (int kd = 0; kd < 3; ++kd) {
            int d2 = 2 * d0 - 1 + kd;
            bool dv = (d2 >= 0 && d2 < D1);
#pragma unroll
            for (int kh = 0; kh < 3; ++kh) {
                int h2 = 2 * ho - 1 + kh;
                bool rvv = dv && (h2 >= 0 && h2 < H1);
                float vm1 = 0.f, v0 = 0.f, v1 = 0.f;
                if (rvv) {
                    int r2 = (d2 * H1 + h2) * W1 + 2 * wo;
                    float2 pb = *(const float2*)(base + r2);
                    v0 = pb.x; v1 = pb.y;
                    if (wo > 0) {
                        float2 pa = *(const float2*)(base + r2 - 2);
                        vm1 = pa.y;
                    }
                }
                const float* wk = wci + kd * 9 + kh * 3;
#pragma unroll
                for (int m = 0; m < 16; ++m)
                    acc[m] += vm1 * wk[m * 432] + v0 * wk[m * 432 + 1] + v1 * wk[m * 432 + 2];
                if (kd >= 1 && kh >= 1) mx = fmaxf(mx, fmaxf(v0, v1));
            }
        }
        float pl = fmaxf(mx, 0.f);
        out[(16 + ci) * N2 + o] = pl;
#pragma unroll
        for (int m = 0; m < 8; ++m) zacc[m] += wzl[m * 32 + 16 + ci] * pl;
    }
#pragma unroll
    for (int j = 0; j < 16; ++j) {
        float cj = fmaxf(acc[j], 0.f);
        out[j * N2 + o] = cj;
#pragma unroll
        for (int m = 0; m < 8; ++m) zacc[m] += wzl[m * 32 + j] * cj;
    }
    float* op = z0i + (size_t)o * 8;
    *(float4*)(op)     = make_float4(fmaxf(zacc[0], 0.f), fmaxf(zacc[1], 0.f),
                                     fmaxf(zacc[2], 0.f), fmaxf(zacc[3], 0.f));
    *(float4*)(op + 4) = make_float4(fmaxf(zacc[4], 0.f), fmaxf(zacc[5], 0.f),
                                     fmaxf(zacc[6], 0.f), fmaxf(zacc[7], 0.f));
}

// ============================================================
// bconv 8ch interleaved [N2][8]: (KD,KH,KW), bias, NADD residuals, relu
// ============================================================
template <int KD, int KH, int KW, int NADD>
__global__ void __launch_bounds__(256) kz_bconv8i(const float* __restrict__ in,
                                                  const float* __restrict__ w,
                                                  const float* __restrict__ b,
                                                  const float* __restrict__ add1,
                                                  const float* __restrict__ add2,
                                                  float* __restrict__ out) {
    constexpr int S = KD * KH * KW;
    __shared__ float wl[64 * S];
    __shared__ float bl[8];
    for (int t = threadIdx.x; t < 64 * S; t += 256) wl[t] = w[t];
    if (threadIdx.x < 8) bl[threadIdx.x] = b[threadIdx.x];
    __syncthreads();
    int o = blockIdx.x * 256 + threadIdx.x;
    if (o >= N2) return;
    int wo = o % W2;
    int t  = o / W2;
    int ho = t % H2;
    int d0 = t / H2;
    float acc[8];
#pragma unroll
    for (int m = 0; m < 8; ++m) acc[m] = bl[m];
#pragma unroll
    for (int kd = 0; kd < KD; ++kd) {
        int d2 = d0 + kd - KD / 2;
        if (KD > 1 && (d2 < 0 || d2 >= D2)) continue;
#pragma unroll
        for (int kh = 0; kh < KH; ++kh) {
            int h2 = ho + kh - KH / 2;
            if (KH > 1 && (h2 < 0 || h2 >= H2)) continue;
#pragma unroll
            for (int kw = 0; kw < KW; ++kw) {
                int w2 = wo + kw - KW / 2;
                if (KW > 1 && (w2 < 0 || w2 >= W2)) continue;
                const float* vp = in + (size_t)((d2 * H2 + h2) * W2 + w2) * 8;
                float4 v0 = *(const float4*)(vp);
                float4 v1 = *(const float4*)(vp + 4);
                int tap = (kd * KH + kh) * KW + kw;
                const float* wt = wl + tap;
#pragma unroll
                for (int m = 0; m < 8; ++m) {
                    const float* wm = wt + m * 8 * S;
                    acc[m] += v0.x * wm[0] + v0.y * wm[S] + v0.z * wm[2 * S] + v0.w * wm[3 * S]
                            + v1.x * wm[4 * S] + v1.y * wm[5 * S] + v1.z * wm[6 * S] + v1.w * wm[7 * S];
                }
            }
        }
    }
    if (NADD >= 1) {
        const float* ap = add1 + (size_t)o * 8;
        float4 r0 = *(const float4*)(ap), r1 = *(const float4*)(ap + 4);
        acc[0] += r0.x; acc[1] += r0.y; acc[2] += r0.z; acc[3] += r0.w;
        acc[4] += r1.x; acc[5] += r1.y; acc[6] += r1.z; acc[7] += r1.w;
    }
    if (NADD >= 2) {
        const float* ap = add2 + (size_t)o * 8;
        float4 r0 = *(const float4*)(ap), r1 = *(const float4*)(ap + 4);
        acc[0] += r0.x; acc[1] += r0.y; acc[2] += r0.z; acc[3] += r0.w;
        acc[4] += r1.x; acc[5] += r1.y; acc[6] += r1.z; acc[7] += r1.w;
    }
    float* op = out + (size_t)o * 8;
    *(float4*)(op)     = make_float4(fmaxf(acc[0], 0.f), fmaxf(acc[1], 0.f),
                                     fmaxf(acc[2], 0.f), fmaxf(acc[3], 0.f));
    *(float4*)(op + 4) = make_float4(fmaxf(acc[4], 0.f), fmaxf(acc[5], 0.f),
                                     fmaxf(acc[6], 0.f), fmaxf(acc[7], 0.f));
}

// ============================================================
// FUSED: bconv8 (3,1,3) + bias + 2 residuals + relu -> z3 (regs)
//        -> pw 8->32 + residual(x2 planar) + relu -> d_out planar [32][N2]
// ============================================================
__global__ void __launch_bounds__(256) kz_bconv8i_pw(const float* __restrict__ in,
                                                     const float* __restrict__ w,
                                                     const float* __restrict__ b,
                                                     const float* __restrict__ add1,
                                                     const float* __restrict__ add2,
                                                     const float* __restrict__ wp,  // (32,8)
                                                     const float* __restrict__ resp,
                                                     float* __restrict__ out) {
    constexpr int S = 9;   // 3*1*3
    __shared__ float wl[64 * S];
    __shared__ float bl[8];
    __shared__ float wpl[256];
    for (int t = threadIdx.x; t < 64 * S; t += 256) wl[t] = w[t];
    if (threadIdx.x < 8) bl[threadIdx.x] = b[threadIdx.x];
    if (threadIdx.x < 256) wpl[threadIdx.x] = wp[threadIdx.x];
    __syncthreads();
    int o = blockIdx.x * 256 + threadIdx.x;
    if (o >= N2) return;
    int wo = o % W2;
    int t  = o / W2;
    int ho = t % H2;
    int d0 = t / H2;
    float acc[8];
#pragma unroll
    for (int m = 0; m < 8; ++m) acc[m] = bl[m];
#pragma unroll
    for (int kd = 0; kd < 3; ++kd) {
        int d2 = d0 + kd - 1;
        if (d2 < 0 || d2 >= D2) continue;
#pragma unroll
        for (int kw = 0; kw < 3; ++kw) {
            int w2 = wo + kw - 1;
            if (w2 < 0 || w2 >= W2) continue;
            const float* vp = in + (size_t)((d2 * H2 + ho) * W2 + w2) * 8;
            float4 v0 = *(const float4*)(vp);
            float4 v1 = *(const float4*)(vp + 4);
            int tap = kd * 3 + kw;
            const float* wt = wl + tap;
#pragma unroll
            for (int m = 0; m < 8; ++m) {
                const float* wm = wt + m * 8 * S;
                acc[m] += v0.x * wm[0] + v0.y * wm[S] + v0.z * wm[2 * S] + v0.w * wm[3 * S]
                        + v1.x * wm[4 * S] + v1.y * wm[5 * S] + v1.z * wm[6 * S] + v1.w * wm[7 * S];
            }
        }
    }
    {
        const float* ap = add1 + (size_t)o * 8;
        float4 r0 = *(const float4*)(ap), r1 = *(const float4*)(ap + 4);
        acc[0] += r0.x; acc[1] += r0.y; acc[2] += r0.z; acc[3] += r0.w;
        acc[4] += r1.x; acc[5] += r1.y; acc[6] += r1.z; acc[7] += r1.w;
    }
    {
        const float* ap = add2 + (size_t)o * 8;
        float4 r0 = *(const float4*)(ap), r1 = *(const float4*)(ap + 4);
        acc[0] += r0.x; acc[1] += r0.y; acc[2] += r0.z; acc[3] += r0.w;
        acc[4] += r1.x; acc[5] += r1.y; acc[6] += r1.z; acc[7] += r1.w;
    }
#pragma unroll
    for (int m = 0; m < 8; ++m) acc[m] = fmaxf(acc[m], 0.f);
#pragma unroll
    for (int m = 0; m < 32; ++m) {
        const float* wm = wpl + m * 8;
        float r = acc[0] * wm[0] + acc[1] * wm[1] + acc[2] * wm[2] + acc[3] * wm[3]
                + acc[4] * wm[4] + acc[5] * wm[5] + acc[6] * wm[6] + acc[7] * wm[7];
        r += resp[(size_t)m * N2 + o];
        out[(size_t)m * N2 + o] = fmaxf(r, 0.f);
    }
}

// ============================================================
extern "C" void kernel_launch(void* const* d_in, const int* in_sizes, int n_in,
                              void* d_out, int out_size, void* d_ws, size_t ws_size,
                              hipStream_t stream) {
    const float* feat   = (const float*)d_in[0];
    const int*   depth  = (const int*)d_in[1];
    const float* w_ds1  = (const float*)d_in[2];
    const float* b1_win = (const float*)d_in[3];
    const float* b1w133 = (const float*)d_in[4];
    const float* b1b133 = (const float*)d_in[5];
    const float* b1w331 = (const float*)d_in[6];
    const float* b1b331 = (const float*)d_in[7];
    const float* b1w313 = (const float*)d_in[8];
    const float* b1b313 = (const float*)d_in[9];
    const float* b1wout = (const float*)d_in[10];
    const float* w_ds2  = (const float*)d_in[11];
    const float* b2_win = (const float*)d_in[12];
    const float* b2w133 = (const float*)d_in[13];
    const float* b2b133 = (const float*)d_in[14];
    const float* b2w331 = (const float*)d_in[15];
    const float* b2b331 = (const float*)d_in[16];
    const float* b2w313 = (const float*)d_in[17];
    const float* b2b313 = (const float*)d_in[18];
    const float* b2wout = (const float*)d_in[19];

    char* base = (char*)d_ws;

    // --- Region layout (time-shared; peak = 265.4 MB, proven safe) ---
    u16* segu = (u16*)base;                               // [0, 199): 3 groups [V][4], filled in-place
    unsigned* winner = (unsigned*)(base + SEG_BYTES);     // [199, 232)
    u16*      tmpu   = (u16*)(base + SEG_BYTES);          // [199, 265) after winner dies
    float*    x1i    = (float*)(base + SEG_BYTES);        // [N1][16] f32 in [199, 265)
    float* y0i = (float*)base;                            // [N1][4] each, after segu dies
    float* y1i = y0i + 4 * N1;
    float* y2i = y1i + 4 * N1;                            // y* occupy [0, 50)
    float* x1b = (float*)(base + GRP_BYTES);              // planar [16][N1], [66.35, 132.7)
    float* x2  = (float*)base;                            // planar [32][N2], after y dead
    float* z0i = x2 + 32 * N2;                            // [N2][8] each
    float* z1i = z0i + 8 * N2;
    float* z2i = z1i + 8 * N2;                            // ends ~29 MB < x1b start

    float* out = (float*)d_out;   // reference output dtype is float32

    // 1. zero volume + winner (contiguous)
    kz_zero16<<<ZCHUNKS / 256, 256, 0, stream>>>((uint4*)base, ZCHUNKS);

    // 2. deterministic last-write-wins scatter
    kz_scatter_win  <<<NPIX / 256, 256, 0, stream>>>(depth, winner);
    kz_scatter_write<<<NPIX / 256, 256, 0, stream>>>(depth, winner, feat, segu);

    // 3. avg-pool hole-fill, 2-pass per group, in-place (R9-proven)
    for (int g = 0; g < 3; ++g) {
        u16* gb = segu + (size_t)g * GRP_U16;
        kz_sumwI<<<(V / 2) / 256, 256, 0, stream>>>(gb, tmpu);
        kz_fillI<<<(V / 2) / 256, 256, 0, stream>>>(gb, tmpu);
    }

    // 4. downsample 1 -> x1 interleaved [N1][16] (clustered stores)
    kz_ds1<<<N1 / 256, 256, 0, stream>>>(segu, w_ds1, x1i);

    // 5. bottleneck 1 (interleaved [N1][4]); last bconv fused with pw4->16
    kz_pw16to4i<<<N1 / 256, 256, 0, stream>>>(x1i, b1_win, y0i);
    kz_bconv4i<1, 3, 3, 0><<<N1 / 256, 256, 0, stream>>>(y0i, b1w133, b1b133, nullptr, nullptr, y1i);
    kz_bconv4i<3, 3, 1, 1><<<N1 / 256, 256, 0, stream>>>(y1i, b1w331, b1b331, y1i, nullptr, y2i);
    kz_bconv4i_pw<<<N1 / 256, 256, 0, stream>>>(y2i, b1w313, b1b313, y2i, y1i, b1wout, x1i, x1b);

    // 6. downsample 2 fused with pw32->8 -> x2 planar + z0 interleaved
    kz_ds2f<<<(N2 + 255) / 256, 256, 0, stream>>>(x1b, w_ds2, b2_win, x2, z0i);

    // 7. bottleneck 2 (interleaved [N2][8]); last bconv fused with pw8->32
    kz_bconv8i<1, 3, 3, 0><<<(N2 + 255) / 256, 256, 0, stream>>>(z0i, b2w133, b2b133, nullptr, nullptr, z1i);
    kz_bconv8i<3, 3, 1, 1><<<(N2 + 255) / 256, 256, 0, stream>>>(z1i, b2w331, b2b331, z1i, nullptr, z2i);
    kz_bconv8i_pw<<<(N2 + 255) / 256, 256, 0, stream>>>(z2i, b2w313, b2b313, z2i, z1i, b2wout, x2, out);

    (void)in_sizes; (void)n_in; (void)out_size; (void)ws_size;
}

// Round 13
// 734.589 us; speedup vs baseline: 1.2871x; 1.1195x over previous
//
#include <hip/hip_runtime.h>
#include <hip/hip_bf16.h>

typedef __hip_bfloat16 bf16;
typedef unsigned short u16;

// bf16 bits -> f32 (exact)
static __device__ __forceinline__ float lo16(unsigned u) { return __uint_as_float(u << 16); }
static __device__ __forceinline__ float hi16(unsigned u) { return __uint_as_float(u & 0xFFFF0000u); }
// f32 -> bf16 bits, round-to-nearest-even (no NaNs in this pipeline)
static __device__ __forceinline__ unsigned f2u(float x) {
    unsigned u = __float_as_uint(x);
    return (u + 0x7FFFu + ((u >> 16) & 1u)) >> 16;
}
static __device__ __forceinline__ unsigned pack2(float a, float b) {
    return f2u(a) | (f2u(b) << 16);
}

// ---- problem constants ----
constexpr int D0 = 240, H0 = 144, W0 = 240;
constexpr int V  = D0 * H0 * W0;          // 8,294,400 voxels
constexpr int NPIX = 480 * 640;           // 307,200 pixels
constexpr int D1 = 120, H1 = 72, W1 = 120;
constexpr int N1 = D1 * H1 * W1;          // 1,036,800
constexpr int D2 = 60, H2 = 36, W2 = 60;
constexpr int N2 = D2 * H2 * W2;          // 129,600

// Volume layout: 3 groups x [V][4] bf16 (channel ci = 4*g + c)
constexpr size_t GRP_U16  = (size_t)V * 4;                    // u16 per group
constexpr size_t GRP_BYTES = GRP_U16 * sizeof(u16);           // 66,355,200
constexpr size_t SEG_BYTES = 3 * GRP_BYTES;                   // 199,065,600
constexpr size_t WIN_BYTES = (size_t)V * sizeof(unsigned);    // 33,177,600
constexpr int ZCHUNKS = (int)((SEG_BYTES + WIN_BYTES) / 16);  // 14,515,200 uint4
// Peak ws: SEG_BYTES + GRP_BYTES = 265,420,800 bytes — proven safe.

// ============================================================
// Zero-fill (uint4)
// ============================================================
__global__ void __launch_bounds__(256) kz_zero16(uint4* __restrict__ p, int nchunks) {
    int i = blockIdx.x * 256 + threadIdx.x;
    if (i >= nchunks) return;
    p[i] = make_uint4(0u, 0u, 0u, 0u);
}

// ============================================================
// Scatter: last-write-wins via winner = max(pixel_index+1)
// ============================================================
__global__ void __launch_bounds__(256) kz_scatter_win(const int* __restrict__ depth,
                                                      unsigned* __restrict__ winner) {
    int p = blockIdx.x * 256 + threadIdx.x;
    if (p >= NPIX) return;
    int d = depth[p];
    if (d > 0 && d < V) atomicMax(&winner[d], (unsigned)(p + 1));
}

__global__ void __launch_bounds__(256) kz_scatter_write(const int* __restrict__ depth,
                                                        const unsigned* __restrict__ winner,
                                                        const float* __restrict__ feat,
                                                        u16* __restrict__ seg) {
    int p = blockIdx.x * 256 + threadIdx.x;
    if (p >= NPIX) return;
    int d = depth[p];
    if (d > 0 && d < V && winner[d] == (unsigned)(p + 1)) {
#pragma unroll
        for (int g = 0; g < 3; ++g) {
            uint2 val;
            val.x = pack2(feat[(4 * g + 0) * NPIX + p], feat[(4 * g + 1) * NPIX + p]);
            val.y = pack2(feat[(4 * g + 2) * NPIX + p], feat[(4 * g + 3) * NPIX + p]);
            *(uint2*)(seg + g * GRP_U16 + (size_t)d * 4) = val;
        }
    }
}

// ============================================================
// One-pass LDS-shared avg-pool hole-fill (one group [V][4]).
// Block tile: 4d x 4h x 120w outputs. Phase 1: 3-tap W row-sums (bf16,
// identical numerics to the proven 2-pass) for the 36 halo rows into LDS.
// Phase 2: 9-row LDS sum, /27, select vs raw, write OUT-OF-PLACE to fb.
// ============================================================
constexpr int FTW = 120;
constexpr int FROWS = 36;   // (4+2) d-rows x (4+2) h-rows

__global__ void __launch_bounds__(256) kz_fillL(const u16* __restrict__ rb,
                                                u16* __restrict__ fb) {
    __shared__ u16 S[FROWS * FTW * 4];   // 34,560 B
    int bid = blockIdx.x;                 // grid: 60*36*2 = 4320
    int wt = bid & 1;
    int t1 = bid >> 1;
    int ht = t1 % 36;
    int dt = t1 / 36;
    int d0 = dt * 4, h0 = ht * 4, w0 = wt * 120;
    int tid = threadIdx.x;

    // Phase 1: 36 rows x 60 voxel-pair tasks
    for (int tt = tid; tt < FROWS * 60; tt += 256) {
        int hr = tt / 60;
        int pt = tt - hr * 60;
        int w = w0 + 2 * pt;
        int d = d0 - 1 + hr / 6;
        int h = h0 - 1 + hr % 6;
        uint4 O = make_uint4(0u, 0u, 0u, 0u);
        if (d >= 0 && d < D0 && h >= 0 && h < H0) {
            const u16* rp = rb + (size_t)((d * H0 + h) * W0 + w) * 4;
            uint4 X = *(const uint4*)(rp);
            float x0[4] = {lo16(X.x), hi16(X.x), lo16(X.y), hi16(X.y)};
            float x1[4] = {lo16(X.z), hi16(X.z), lo16(X.w), hi16(X.w)};
            float l[4] = {0.f, 0.f, 0.f, 0.f}, rr[4] = {0.f, 0.f, 0.f, 0.f};
            if (w > 0) {
                uint2 L = *(const uint2*)(rp - 4);
                l[0] = lo16(L.x); l[1] = hi16(L.x); l[2] = lo16(L.y); l[3] = hi16(L.y);
            }
            if (w < 238) {
                uint2 R = *(const uint2*)(rp + 8);
                rr[0] = lo16(R.x); rr[1] = hi16(R.x); rr[2] = lo16(R.y); rr[3] = hi16(R.y);
            }
            O.x = pack2(l[0] + x0[0] + x1[0], l[1] + x0[1] + x1[1]);
            O.y = pack2(l[2] + x0[2] + x1[2], l[3] + x0[3] + x1[3]);
            O.z = pack2(x0[0] + x1[0] + rr[0], x0[1] + x1[1] + rr[1]);
            O.w = pack2(x0[2] + x1[2] + rr[2], x0[3] + x1[3] + rr[3]);
        }
        *(uint4*)(S + ((size_t)hr * FTW + 2 * pt) * 4) = O;
    }
    __syncthreads();

    // Phase 2: 16 output rows x 60 voxel-pair tasks
    for (int ot = tid; ot < 16 * 60; ot += 256) {
        int orr = ot / 60;
        int pt = ot - orr * 60;
        int w = w0 + 2 * pt;
        int di = orr >> 2, hi_ = orr & 3;
        int d = d0 + di, h = h0 + hi_;
        float s[8] = {0.f, 0.f, 0.f, 0.f, 0.f, 0.f, 0.f, 0.f};
#pragma unroll
        for (int dd = 0; dd < 3; ++dd) {
#pragma unroll
            for (int dh = 0; dh < 3; ++dh) {
                int hr = (di + dd) * 6 + (hi_ + dh);
                uint4 T = *(const uint4*)(S + ((size_t)hr * FTW + 2 * pt) * 4);
                s[0] += lo16(T.x); s[1] += hi16(T.x); s[2] += lo16(T.y); s[3] += hi16(T.y);
                s[4] += lo16(T.z); s[5] += hi16(T.z); s[6] += lo16(T.w); s[7] += hi16(T.w);
            }
        }
        size_t gi = (size_t)((d * H0 + h) * W0 + w) * 4;
        uint4 Rv = *(const uint4*)(rb + gi);
        constexpr float inv27 = 1.0f / 27.0f;
        uint4 Ov;
        Ov.x = ((Rv.x & 0x7FFFu) ? (Rv.x & 0xFFFFu) : f2u(s[0] * inv27))
             | ((((Rv.x >> 16) & 0x7FFFu) ? (Rv.x >> 16) : f2u(s[1] * inv27)) << 16);
        Ov.y = ((Rv.y & 0x7FFFu) ? (Rv.y & 0xFFFFu) : f2u(s[2] * inv27))
             | ((((Rv.y >> 16) & 0x7FFFu) ? (Rv.y >> 16) : f2u(s[3] * inv27)) << 16);
        Ov.z = ((Rv.z & 0x7FFFu) ? (Rv.z & 0xFFFFu) : f2u(s[4] * inv27))
             | ((((Rv.z >> 16) & 0x7FFFu) ? (Rv.z >> 16) : f2u(s[5] * inv27)) << 16);
        Ov.w = ((Rv.w & 0x7FFFu) ? (Rv.w & 0xFFFFu) : f2u(s[6] * inv27))
             | ((((Rv.w >> 16) & 0x7FFFu) ? (Rv.w >> 16) : f2u(s[7] * inv27)) << 16);
        *(uint4*)(fb + gi) = Ov;
    }
}

// ============================================================
// Downsample 1: conv 12->4 (k3,s2,p1) ++ maxpool2, relu.
// 3 filled group pointers; pool channels stashed in LDS; clustered stores.
// (R12-proven body)
// ============================================================
__global__ void __launch_bounds__(256) kz_ds1(const u16* __restrict__ f0g,
                                              const u16* __restrict__ f1g,
                                              const u16* __restrict__ f2g,
                                              const float* __restrict__ w,
                                              float* __restrict__ x1i) {
    __shared__ float wl[4 * 12 * 27];
    __shared__ float pool[12 * 256];
    for (int t = threadIdx.x; t < 4 * 12 * 27; t += 256) wl[t] = w[t];
    __syncthreads();
    int tid = threadIdx.x;
    int o = blockIdx.x * 256 + tid;    // grid exact: N1/256 = 4050
    int wo = o % W1;
    int t  = o / W1;
    int ho = t % H1;
    int d0 = t / H1;
    float acc[4] = {0.f, 0.f, 0.f, 0.f};
#pragma unroll 1
    for (int g = 0; g < 3; ++g) {
        const u16* base = (g == 0) ? f0g : ((g == 1) ? f1g : f2g);
        const float* wg = wl + (4 * g) * 27;
        float mx0 = -1e30f, mx1 = -1e30f, mx2 = -1e30f, mx3 = -1e30f;
#pragma unroll 1
        for (int kd = 0; kd < 3; ++kd) {
            int d2 = 2 * d0 - 1 + kd;
            bool dv = (d2 >= 0 && d2 < D0);
#pragma unroll
            for (int kh = 0; kh < 3; ++kh) {
                int h2 = 2 * ho - 1 + kh;
                bool rvv = dv && (h2 >= 0 && h2 < H0);
                float a0 = 0.f, a1 = 0.f, a2 = 0.f, a3 = 0.f;
                float b0 = 0.f, b1 = 0.f, b2 = 0.f, b3 = 0.f;
                float c0 = 0.f, c1 = 0.f, c2 = 0.f, c3 = 0.f;
                if (rvv) {
                    size_t r2 = (size_t)((d2 * H0 + h2) * W0 + 2 * wo);
                    uint4 AB = *(const uint4*)(base + r2 * 4);
                    b0 = lo16(AB.x); b1 = hi16(AB.x); b2 = lo16(AB.y); b3 = hi16(AB.y);
                    c0 = lo16(AB.z); c1 = hi16(AB.z); c2 = lo16(AB.w); c3 = hi16(AB.w);
                    if (wo > 0) {
                        uint2 P = *(const uint2*)(base + (r2 - 1) * 4);
                        a0 = lo16(P.x); a1 = hi16(P.x); a2 = lo16(P.y); a3 = hi16(P.y);
                    }
                }
                const float* wk = wg + kd * 9 + kh * 3;
#pragma unroll
                for (int m = 0; m < 4; ++m) {
                    const float* wm = wk + m * 324;
                    acc[m] += a0 * wm[0]  + b0 * wm[1]  + c0 * wm[2]
                            + a1 * wm[27] + b1 * wm[28] + c1 * wm[29]
                            + a2 * wm[54] + b2 * wm[55] + c2 * wm[56]
                            + a3 * wm[81] + b3 * wm[82] + c3 * wm[83];
                }
                if (kd >= 1 && kh >= 1) {
                    mx0 = fmaxf(mx0, fmaxf(b0, c0));
                    mx1 = fmaxf(mx1, fmaxf(b1, c1));
                    mx2 = fmaxf(mx2, fmaxf(b2, c2));
                    mx3 = fmaxf(mx3, fmaxf(b3, c3));
                }
            }
        }
        pool[(4 * g + 0) * 256 + tid] = fmaxf(mx0, 0.f);
        pool[(4 * g + 1) * 256 + tid] = fmaxf(mx1, 0.f);
        pool[(4 * g + 2) * 256 + tid] = fmaxf(mx2, 0.f);
        pool[(4 * g + 3) * 256 + tid] = fmaxf(mx3, 0.f);
    }
    float* xo = x1i + (size_t)o * 16;
    *(float4*)(xo)      = make_float4(fmaxf(acc[0], 0.f), fmaxf(acc[1], 0.f),
                                      fmaxf(acc[2], 0.f), fmaxf(acc[3], 0.f));
    *(float4*)(xo + 4)  = make_float4(pool[0 * 256 + tid], pool[1 * 256 + tid],
                                      pool[2 * 256 + tid], pool[3 * 256 + tid]);
    *(float4*)(xo + 8)  = make_float4(pool[4 * 256 + tid], pool[5 * 256 + tid],
                                      pool[6 * 256 + tid], pool[7 * 256 + tid]);
    *(float4*)(xo + 12) = make_float4(pool[8 * 256 + tid], pool[9 * 256 + tid],
                                      pool[10 * 256 + tid], pool[11 * 256 + tid]);
}

// ============================================================
// pw 16->4: x1 interleaved [N1][16] -> y0 interleaved [N1][4], relu
// ============================================================
__global__ void __launch_bounds__(256) kz_pw16to4i(const float* __restrict__ in,
                                                   const float* __restrict__ w,
                                                   float* __restrict__ out) {
    __shared__ float wl[64];
    if (threadIdx.x < 64) wl[threadIdx.x] = w[threadIdx.x];
    __syncthreads();
    int o = blockIdx.x * 256 + threadIdx.x;   // exact
    const float* ip = in + (size_t)o * 16;
    float4 A = *(const float4*)(ip);
    float4 B = *(const float4*)(ip + 4);
    float4 C = *(const float4*)(ip + 8);
    float4 D = *(const float4*)(ip + 12);
    float r[4];
#pragma unroll
    for (int m = 0; m < 4; ++m) {
        const float* wm = wl + m * 16;
        r[m] = A.x * wm[0] + A.y * wm[1] + A.z * wm[2] + A.w * wm[3]
             + B.x * wm[4] + B.y * wm[5] + B.z * wm[6] + B.w * wm[7]
             + C.x * wm[8] + C.y * wm[9] + C.z * wm[10] + C.w * wm[11]
             + D.x * wm[12] + D.y * wm[13] + D.z * wm[14] + D.w * wm[15];
    }
    *(float4*)(out + (size_t)o * 4) = make_float4(fmaxf(r[0], 0.f), fmaxf(r[1], 0.f),
                                                  fmaxf(r[2], 0.f), fmaxf(r[3], 0.f));
}

// ============================================================
// bconv 4ch interleaved [N1][4]: (KD,KH,KW), bias, NADD residuals, relu
// ============================================================
template <int KD, int KH, int KW, int NADD>
__global__ void __launch_bounds__(256) kz_bconv4i(const float* __restrict__ in,
                                                  const float* __restrict__ w,
                                                  const float* __restrict__ b,
                                                  const float* __restrict__ add1,
                                                  const float* __restrict__ add2,
                                                  float* __restrict__ out) {
    constexpr int S = KD * KH * KW;
    __shared__ float wl[16 * S];
    __shared__ float bl[4];
    for (int t = threadIdx.x; t < 16 * S; t += 256) wl[t] = w[t];
    if (threadIdx.x < 4) bl[threadIdx.x] = b[threadIdx.x];
    __syncthreads();
    int o = blockIdx.x * 256 + threadIdx.x;   // exact: N1/256
    int wo = o % W1;
    int t  = o / W1;
    int ho = t % H1;
    int d0 = t / H1;
    float a0 = bl[0], a1 = bl[1], a2 = bl[2], a3 = bl[3];
#pragma unroll
    for (int kd = 0; kd < KD; ++kd) {
        int d2 = d0 + kd - KD / 2;
        if (KD > 1 && (d2 < 0 || d2 >= D1)) continue;
#pragma unroll
        for (int kh = 0; kh < KH; ++kh) {
            int h2 = ho + kh - KH / 2;
            if (KH > 1 && (h2 < 0 || h2 >= H1)) continue;
#pragma unroll
            for (int kw = 0; kw < KW; ++kw) {
                int w2 = wo + kw - KW / 2;
                if (KW > 1 && (w2 < 0 || w2 >= W1)) continue;
                float4 v = *(const float4*)(in + (size_t)((d2 * H1 + h2) * W1 + w2) * 4);
                int tap = (kd * KH + kh) * KW + kw;
                const float* wt = wl + tap;
                a0 += v.x * wt[0 * S] + v.y * wt[1 * S] + v.z * wt[2 * S] + v.w * wt[3 * S];
                a1 += v.x * wt[4 * S] + v.y * wt[5 * S] + v.z * wt[6 * S] + v.w * wt[7 * S];
                a2 += v.x * wt[8 * S] + v.y * wt[9 * S] + v.z * wt[10 * S] + v.w * wt[11 * S];
                a3 += v.x * wt[12 * S] + v.y * wt[13 * S] + v.z * wt[14 * S] + v.w * wt[15 * S];
            }
        }
    }
    if (NADD >= 1) {
        float4 r1 = *(const float4*)(add1 + (size_t)o * 4);
        a0 += r1.x; a1 += r1.y; a2 += r1.z; a3 += r1.w;
    }
    if (NADD >= 2) {
        float4 r2 = *(const float4*)(add2 + (size_t)o * 4);
        a0 += r2.x; a1 += r2.y; a2 += r2.z; a3 += r2.w;
    }
    *(float4*)(out + (size_t)o * 4) = make_float4(fmaxf(a0, 0.f), fmaxf(a1, 0.f),
                                                  fmaxf(a2, 0.f), fmaxf(a3, 0.f));
}

// ============================================================
// FUSED: bconv4 (3,1,3) + bias + 2 residuals + relu -> pw 4->16
//        + residual(x1i) + relu -> x1b PLANAR [16][N1]
// ============================================================
__global__ void __launch_bounds__(256) kz_bconv4i_pw(const float* __restrict__ in,
                                                     const float* __restrict__ w,
                                                     const float* __restrict__ b,
                                                     const float* __restrict__ add1,
                                                     const float* __restrict__ add2,
                                                     const float* __restrict__ wp,
                                                     const float* __restrict__ x1i,
                                                     float* __restrict__ out) {
    constexpr int S = 9;   // 3*1*3
    __shared__ float wl[16 * S];
    __shared__ float bl[4];
    __shared__ float wpl[64];
    for (int t = threadIdx.x; t < 16 * S; t += 256) wl[t] = w[t];
    if (threadIdx.x < 4) bl[threadIdx.x] = b[threadIdx.x];
    if (threadIdx.x < 64) wpl[threadIdx.x] = wp[threadIdx.x];
    __syncthreads();
    int o = blockIdx.x * 256 + threadIdx.x;   // exact
    int wo = o % W1;
    int t  = o / W1;
    int ho = t % H1;
    int d0 = t / H1;
    float a0 = bl[0], a1 = bl[1], a2 = bl[2], a3 = bl[3];
#pragma unroll
    for (int kd = 0; kd < 3; ++kd) {
        int d2 = d0 + kd - 1;
        if (d2 < 0 || d2 >= D1) continue;
#pragma unroll
        for (int kw = 0; kw < 3; ++kw) {
            int w2 = wo + kw - 1;
            if (w2 < 0 || w2 >= W1) continue;
            float4 v = *(const float4*)(in + (size_t)((d2 * H1 + ho) * W1 + w2) * 4);
            int tap = kd * 3 + kw;
            const float* wt = wl + tap;
            a0 += v.x * wt[0 * S] + v.y * wt[1 * S] + v.z * wt[2 * S] + v.w * wt[3 * S];
            a1 += v.x * wt[4 * S] + v.y * wt[5 * S] + v.z * wt[6 * S] + v.w * wt[7 * S];
            a2 += v.x * wt[8 * S] + v.y * wt[9 * S] + v.z * wt[10 * S] + v.w * wt[11 * S];
            a3 += v.x * wt[12 * S] + v.y * wt[13 * S] + v.z * wt[14 * S] + v.w * wt[15 * S];
        }
    }
    float4 r1 = *(const float4*)(add1 + (size_t)o * 4);
    float4 r2 = *(const float4*)(add2 + (size_t)o * 4);
    float y0 = fmaxf(a0 + r1.x + r2.x, 0.f);
    float y1 = fmaxf(a1 + r1.y + r2.y, 0.f);
    float y2 = fmaxf(a2 + r1.z + r2.z, 0.f);
    float y3 = fmaxf(a3 + r1.w + r2.w, 0.f);
    const float* rp = x1i + (size_t)o * 16;
    float4 R0 = *(const float4*)(rp);
    float4 R1 = *(const float4*)(rp + 4);
    float4 R2 = *(const float4*)(rp + 8);
    float4 R3 = *(const float4*)(rp + 12);
    float rr[16] = {R0.x, R0.y, R0.z, R0.w, R1.x, R1.y, R1.z, R1.w,
                    R2.x, R2.y, R2.z, R2.w, R3.x, R3.y, R3.z, R3.w};
#pragma unroll
    for (int m = 0; m < 16; ++m) {
        const float* wm = wpl + m * 4;
        float r = y0 * wm[0] + y1 * wm[1] + y2 * wm[2] + y3 * wm[3] + rr[m];
        out[(size_t)m * N1 + o] = fmaxf(r, 0.f);
    }
}

// ============================================================
// FUSED Downsample 2 + pw 32->8 (R12-proven)
// ============================================================
__global__ void __launch_bounds__(256) kz_ds2f(const float* __restrict__ in,
                                               const float* __restrict__ w,
                                               const float* __restrict__ wz,
                                               float* __restrict__ out,
                                               float* __restrict__ z0i) {
    __shared__ float wl[16 * 16 * 27];
    __shared__ float wzl[256];
    for (int t = threadIdx.x; t < 16 * 16 * 27; t += 256) wl[t] = w[t];
    if (threadIdx.x < 256) wzl[threadIdx.x] = wz[threadIdx.x];
    __syncthreads();
    int o = blockIdx.x * 256 + threadIdx.x;
    if (o >= N2) return;
    int wo = o % W2;
    int t  = o / W2;
    int ho = t % H2;
    int d0 = t / H2;
    float acc[16];
    float zacc[8];
#pragma unroll
    for (int m = 0; m < 16; ++m) acc[m] = 0.f;
#pragma unroll
    for (int m = 0; m < 8; ++m) zacc[m] = 0.f;
#pragma unroll 1
    for (int ci = 0; ci < 16; ++ci) {
        const float* base = in + ci * N1;
        const float* wci = wl + ci * 27;
        float mx = -1e30f;
#pragma unroll 1
        for (int kd = 0; kd < 3; ++kd) {
            int d2 = 2 * d0 - 1 + kd;
            bool dv = (d2 >= 0 && d2 < D1);
#pragma unroll
            for (int kh = 0; kh < 3; ++kh) {
                int h2 = 2 * ho - 1 + kh;
                bool rvv = dv && (h2 >= 0 && h2 < H1);
                float vm1 = 0.f, v0 = 0.f, v1 = 0.f;
                if (rvv) {
                    int r2 = (d2 * H1 + h2) * W1 + 2 * wo;
                    float2 pb = *(const float2*)(base + r2);
                    v0 = pb.x; v1 = pb.y;
                    if (wo > 0) {
                        float2 pa = *(const float2*)(base + r2 - 2);
                        vm1 = pa.y;
                    }
                }
                const float* wk = wci + kd * 9 + kh * 3;
#pragma unroll
                for (int m = 0; m < 16; ++m)
                    acc[m] += vm1 * wk[m * 432] + v0 * wk[m * 432 + 1] + v1 * wk[m * 432 + 2];
                if (kd >= 1 && kh >= 1) mx = fmaxf(mx, fmaxf(v0, v1));
            }
        }
        float pl = fmaxf(mx, 0.f);
        out[(16 + ci) * N2 + o] = pl;
#pragma unroll
        for (int m = 0; m < 8; ++m) zacc[m] += wzl[m * 32 + 16 + ci] * pl;
    }
#pragma unroll
    for (int j = 0; j < 16; ++j) {
        float cj = fmaxf(acc[j], 0.f);
        out[j * N2 + o] = cj;
#pragma unroll
        for (int m = 0; m < 8; ++m) zacc[m] += wzl[m * 32 + j] * cj;
    }
    float* op = z0i + (size_t)o * 8;
    *(float4*)(op)     = make_float4(fmaxf(zacc[0], 0.f), fmaxf(zacc[1], 0.f),
                                     fmaxf(zacc[2], 0.f), fmaxf(zacc[3], 0.f));
    *(float4*)(op + 4) = make_float4(fmaxf(zacc[4], 0.f), fmaxf(zacc[5], 0.f),
                                     fmaxf(zacc[6], 0.f), fmaxf(zacc[7], 0.f));
}

// ============================================================
// bconv 8ch interleaved [N2][8] (R12-proven)
// ============================================================
template <int KD, int KH, int KW, int NADD>
__global__ void __launch_bounds__(256) kz_bconv8i(const float* __restrict__ in,
                                                  const float* __restrict__ w,
                                                  const float* __restrict__ b,
                                                  const float* __restrict__ add1,
                                                  const float* __restrict__ add2,
                                                  float* __restrict__ out) {
    constexpr int S = KD * KH * KW;
    __shared__ float wl[64 * S];
    __shared__ float bl[8];
    for (int t = threadIdx.x; t < 64 * S; t += 256) wl[t] = w[t];
    if (threadIdx.x < 8) bl[threadIdx.x] = b[threadIdx.x];
    __syncthreads();
    int o = blockIdx.x * 256 + threadIdx.x;
    if (o >= N2) return;
    int wo = o % W2;
    int t  = o / W2;
    int ho = t % H2;
    int d0 = t / H2;
    float acc[8];
#pragma unroll
    for (int m = 0; m < 8; ++m) acc[m] = bl[m];
#pragma unroll
    for (int kd = 0; kd < KD; ++kd) {
        int d2 = d0 + kd - KD / 2;
        if (KD > 1 && (d2 < 0 || d2 >= D2)) continue;
#pragma unroll
        for (int kh = 0; kh < KH; ++kh) {
            int h2 = ho + kh - KH / 2;
            if (KH > 1 && (h2 < 0 || h2 >= H2)) continue;
#pragma unroll
            for (int kw = 0; kw < KW; ++kw) {
                int w2 = wo + kw - KW / 2;
                if (KW > 1 && (w2 < 0 || w2 >= W2)) continue;
                const float* vp = in + (size_t)((d2 * H2 + h2) * W2 + w2) * 8;
                float4 v0 = *(const float4*)(vp);
                float4 v1 = *(const float4*)(vp + 4);
                int tap = (kd * KH + kh) * KW + kw;
                const float* wt = wl + tap;
#pragma unroll
                for (int m = 0; m < 8; ++m) {
                    const float* wm = wt + m * 8 * S;
                    acc[m] += v0.x * wm[0] + v0.y * wm[S] + v0.z * wm[2 * S] + v0.w * wm[3 * S]
                            + v1.x * wm[4 * S] + v1.y * wm[5 * S] + v1.z * wm[6 * S] + v1.w * wm[7 * S];
                }
            }
        }
    }
    if (NADD >= 1) {
        const float* ap = add1 + (size_t)o * 8;
        float4 r0 = *(const float4*)(ap), r1 = *(const float4*)(ap + 4);
        acc[0] += r0.x; acc[1] += r0.y; acc[2] += r0.z; acc[3] += r0.w;
        acc[4] += r1.x; acc[5] += r1.y; acc[6] += r1.z; acc[7] += r1.w;
    }
    if (NADD >= 2) {
        const float* ap = add2 + (size_t)o * 8;
        float4 r0 = *(const float4*)(ap), r1 = *(const float4*)(ap + 4);
        acc[0] += r0.x; acc[1] += r0.y; acc[2] += r0.z; acc[3] += r0.w;
        acc[4] += r1.x; acc[5] += r1.y; acc[6] += r1.z; acc[7] += r1.w;
    }
    float* op = out + (size_t)o * 8;
    *(float4*)(op)     = make_float4(fmaxf(acc[0], 0.f), fmaxf(acc[1], 0.f),
                                     fmaxf(acc[2], 0.f), fmaxf(acc[3], 0.f));
    *(float4*)(op + 4) = make_float4(fmaxf(acc[4], 0.f), fmaxf(acc[5], 0.f),
                                     fmaxf(acc[6], 0.f), fmaxf(acc[7], 0.f));
}

// ============================================================
// FUSED: bconv8 (3,1,3) + residuals + relu -> pw 8->32 + residual + relu
// -> d_out planar [32][N2] (R12-proven)
// ============================================================
__global__ void __launch_bounds__(256) kz_bconv8i_pw(const float* __restrict__ in,
                                                     const float* __restrict__ w,
                                                     const float* __restrict__ b,
                                                     const float* __restrict__ add1,
                                                     const float* __restrict__ add2,
                                                     const float* __restrict__ wp,
                                                     const float* __restrict__ resp,
                                                     float* __restrict__ out) {
    constexpr int S = 9;   // 3*1*3
    __shared__ float wl[64 * S];
    __shared__ float bl[8];
    __shared__ float wpl[256];
    for (int t = threadIdx.x; t < 64 * S; t += 256) wl[t] = w[t];
    if (threadIdx.x < 8) bl[threadIdx.x] = b[threadIdx.x];
    if (threadIdx.x < 256) wpl[threadIdx.x] = wp[threadIdx.x];
    __syncthreads();
    int o = blockIdx.x * 256 + threadIdx.x;
    if (o >= N2) return;
    int wo = o % W2;
    int t  = o / W2;
    int ho = t % H2;
    int d0 = t / H2;
    float acc[8];
#pragma unroll
    for (int m = 0; m < 8; ++m) acc[m] = bl[m];
#pragma unroll
    for (int kd = 0; kd < 3; ++kd) {
        int d2 = d0 + kd - 1;
        if (d2 < 0 || d2 >= D2) continue;
#pragma unroll
        for (int kw = 0; kw < 3; ++kw) {
            int w2 = wo + kw - 1;
            if (w2 < 0 || w2 >= W2) continue;
            const float* vp = in + (size_t)((d2 * H2 + ho) * W2 + w2) * 8;
            float4 v0 = *(const float4*)(vp);
            float4 v1 = *(const float4*)(vp + 4);
            int tap = kd * 3 + kw;
            const float* wt = wl + tap;
#pragma unroll
            for (int m = 0; m < 8; ++m) {
                const float* wm = wt + m * 8 * S;
                acc[m] += v0.x * wm[0] + v0.y * wm[S] + v0.z * wm[2 * S] + v0.w * wm[3 * S]
                        + v1.x * wm[4 * S] + v1.y * wm[5 * S] + v1.z * wm[6 * S] + v1.w * wm[7 * S];
            }
        }
    }
    {
        const float* ap = add1 + (size_t)o * 8;
        float4 r0 = *(const float4*)(ap), r1 = *(const float4*)(ap + 4);
        acc[0] += r0.x; acc[1] += r0.y; acc[2] += r0.z; acc[3] += r0.w;
        acc[4] += r1.x; acc[5] += r1.y; acc[6] += r1.z; acc[7] += r1.w;
    }
    {
        const float* ap = add2 + (size_t)o * 8;
        float4 r0 = *(const float4*)(ap), r1 = *(const float4*)(ap + 4);
        acc[0] += r0.x; acc[1] += r0.y; acc[2] += r0.z; acc[3] += r0.w;
        acc[4] += r1.x; acc[5] += r1.y; acc[6] += r1.z; acc[7] += r1.w;
    }
#pragma unroll
    for (int m = 0; m < 8; ++m) acc[m] = fmaxf(acc[m], 0.f);
#pragma unroll
    for (int m = 0; m < 32; ++m) {
        const float* wm = wpl + m * 8;
        float r = acc[0] * wm[0] + acc[1] * wm[1] + acc[2] * wm[2] + acc[3] * wm[3]
                + acc[4] * wm[4] + acc[5] * wm[5] + acc[6] * wm[6] + acc[7] * wm[7];
        r += resp[(size_t)m * N2 + o];
        out[(size_t)m * N2 + o] = fmaxf(r, 0.f);
    }
}

// ============================================================
extern "C" void kernel_launch(void* const* d_in, const int* in_sizes, int n_in,
                              void* d_out, int out_size, void* d_ws, size_t ws_size,
                              hipStream_t stream) {
    const float* feat   = (const float*)d_in[0];
    const int*   depth  = (const int*)d_in[1];
    const float* w_ds1  = (const float*)d_in[2];
    const float* b1_win = (const float*)d_in[3];
    const float* b1w133 = (const float*)d_in[4];
    const float* b1b133 = (const float*)d_in[5];
    const float* b1w331 = (const float*)d_in[6];
    const float* b1b331 = (const float*)d_in[7];
    const float* b1w313 = (const float*)d_in[8];
    const float* b1b313 = (const float*)d_in[9];
    const float* b1wout = (const float*)d_in[10];
    const float* w_ds2  = (const float*)d_in[11];
    const float* b2_win = (const float*)d_in[12];
    const float* b2w133 = (const float*)d_in[13];
    const float* b2b133 = (const float*)d_in[14];
    const float* b2w331 = (const float*)d_in[15];
    const float* b2b331 = (const float*)d_in[16];
    const float* b2w313 = (const float*)d_in[17];
    const float* b2b313 = (const float*)d_in[18];
    const float* b2wout = (const float*)d_in[19];

    char* base = (char*)d_ws;

    // --- Region layout (time-shared; peak = 265.4 MB, proven safe) ---
    // Phase A: raw groups [0,66.35) [66.35,132.7) [132.7,199.07); winner [199.07,232.2)
    u16* raw0 = (u16*)base;
    u16* raw1 = (u16*)(base + GRP_BYTES);
    u16* raw2 = (u16*)(base + 2 * GRP_BYTES);
    unsigned* winner = (unsigned*)(base + SEG_BYTES);
    // Phase B: fill rotates out-of-place into dead regions (launch-ordered):
    u16* fil0 = (u16*)(base + SEG_BYTES);      // [199.07, 265.4) — winner dead
    u16* fil1 = (u16*)base;                    // [0, 66.35)     — raw0 dead after fill g0
    u16* fil2 = (u16*)(base + GRP_BYTES);      // [66.35, 132.7) — raw1 dead after fill g1
    // Phase C: ds1 -> x1i [N1][16] at [132.7, 199.07) (raw2 dead after fill g2)
    float* x1i = (float*)(base + 2 * GRP_BYTES);
    // Phase D (fil* dead after ds1): y* interleaved in [0, 49.8)
    float* y0i = (float*)base;
    float* y1i = y0i + 4 * N1;
    float* y2i = y1i + 4 * N1;
    float* x1b = (float*)(base + SEG_BYTES);   // planar [16][N1] at [199.07, 265.4) (fil0 dead)
    // Phase E (y dead): x2 planar + z* interleaved in [0, 29)
    float* x2  = (float*)base;
    float* z0i = x2 + 32 * N2;
    float* z1i = z0i + 8 * N2;
    float* z2i = z1i + 8 * N2;

    float* out = (float*)d_out;   // reference output dtype is float32

    // 1. zero raw volume + winner (contiguous)
    kz_zero16<<<ZCHUNKS / 256, 256, 0, stream>>>((uint4*)base, ZCHUNKS);

    // 2. deterministic last-write-wins scatter
    kz_scatter_win  <<<NPIX / 256, 256, 0, stream>>>(depth, winner);
    kz_scatter_write<<<NPIX / 256, 256, 0, stream>>>(depth, winner, feat, raw0);

    // 3. one-pass LDS-shared hole-fill, per group, out-of-place (rotating)
    kz_fillL<<<4320, 256, 0, stream>>>(raw0, fil0);
    kz_fillL<<<4320, 256, 0, stream>>>(raw1, fil1);
    kz_fillL<<<4320, 256, 0, stream>>>(raw2, fil2);

    // 4. downsample 1 -> x1 interleaved [N1][16]
    kz_ds1<<<N1 / 256, 256, 0, stream>>>(fil0, fil1, fil2, w_ds1, x1i);

    // 5. bottleneck 1 (interleaved [N1][4]); last bconv fused with pw4->16
    kz_pw16to4i<<<N1 / 256, 256, 0, stream>>>(x1i, b1_win, y0i);
    kz_bconv4i<1, 3, 3, 0><<<N1 / 256, 256, 0, stream>>>(y0i, b1w133, b1b133, nullptr, nullptr, y1i);
    kz_bconv4i<3, 3, 1, 1><<<N1 / 256, 256, 0, stream>>>(y1i, b1w331, b1b331, y1i, nullptr, y2i);
    kz_bconv4i_pw<<<N1 / 256, 256, 0, stream>>>(y2i, b1w313, b1b313, y2i, y1i, b1wout, x1i, x1b);

    // 6. downsample 2 fused with pw32->8 -> x2 planar + z0 interleaved
    kz_ds2f<<<(N2 + 255) / 256, 256, 0, stream>>>(x1b, w_ds2, b2_win, x2, z0i);

    // 7. bottleneck 2 (interleaved [N2][8]); last bconv fused with pw8->32
    kz_bconv8i<1, 3, 3, 0><<<(N2 + 255) / 256, 256, 0, stream>>>(z0i, b2w133, b2b133, nullptr, nullptr, z1i);
    kz_bconv8i<3, 3, 1, 1><<<(N2 + 255) / 256, 256, 0, stream>>>(z1i, b2w331, b2b331, z1i, nullptr, z2i);
    kz_bconv8i_pw<<<(N2 + 255) / 256, 256, 0, stream>>>(z2i, b2w313, b2b313, z2i, z1i, b2wout, x2, out);

    (void)in_sizes; (void)n_in; (void)out_size; (void)ws_size;
}

// Round 14
// 732.335 us; speedup vs baseline: 1.2911x; 1.0031x over previous
//
#include <hip/hip_runtime.h>
#include <hip/hip_bf16.h>

typedef __hip_bfloat16 bf16;
typedef unsigned short u16;

// bf16 bits -> f32 (exact)
static __device__ __forceinline__ float lo16(unsigned u) { return __uint_as_float(u << 16); }
static __device__ __forceinline__ float hi16(unsigned u) { return __uint_as_float(u & 0xFFFF0000u); }
// f32 -> bf16 bits, round-to-nearest-even (no NaNs in this pipeline)
static __device__ __forceinline__ unsigned f2u(float x) {
    unsigned u = __float_as_uint(x);
    return (u + 0x7FFFu + ((u >> 16) & 1u)) >> 16;
}
static __device__ __forceinline__ unsigned pack2(float a, float b) {
    return f2u(a) | (f2u(b) << 16);
}

// ---- problem constants ----
constexpr int D0 = 240, H0 = 144, W0 = 240;
constexpr int V  = D0 * H0 * W0;          // 8,294,400 voxels
constexpr int NPIX = 480 * 640;           // 307,200 pixels
constexpr int D1 = 120, H1 = 72, W1 = 120;
constexpr int N1 = D1 * H1 * W1;          // 1,036,800
constexpr int D2 = 60, H2 = 36, W2 = 60;
constexpr int N2 = D2 * H2 * W2;          // 129,600

// Volume layout: 3 groups x [V][4] bf16 (channel ci = 4*g + c)
constexpr size_t GRP_U16  = (size_t)V * 4;                    // u16 per group
constexpr size_t GRP_BYTES = GRP_U16 * sizeof(u16);           // 66,355,200
constexpr size_t SEG_BYTES = 3 * GRP_BYTES;                   // 199,065,600
constexpr size_t WIN_BYTES = (size_t)V * sizeof(unsigned);    // 33,177,600
constexpr int ZCHUNKS  = (int)((SEG_BYTES + WIN_BYTES) / 16); // 14,515,200 uint4
constexpr int WCHUNKS  = (int)(WIN_BYTES / 16);               // 2,073,600 uint4
constexpr size_t BIG_WS = SEG_BYTES + WIN_BYTES + GRP_BYTES;  // 298,598,400

// ============================================================
// Zero-fill (uint4)
// ============================================================
__global__ void __launch_bounds__(256) kz_zero16(uint4* __restrict__ p, int nchunks) {
    int i = blockIdx.x * 256 + threadIdx.x;
    if (i >= nchunks) return;
    p[i] = make_uint4(0u, 0u, 0u, 0u);
}

// ============================================================
// Scatter: last-write-wins via winner = max(pixel_index+1)
// ============================================================
__global__ void __launch_bounds__(256) kz_scatter_win(const int* __restrict__ depth,
                                                      unsigned* __restrict__ winner) {
    int p = blockIdx.x * 256 + threadIdx.x;
    if (p >= NPIX) return;
    int d = depth[p];
    if (d > 0 && d < V) atomicMax(&winner[d], (unsigned)(p + 1));
}

__global__ void __launch_bounds__(256) kz_scatter_write(const int* __restrict__ depth,
                                                        const unsigned* __restrict__ winner,
                                                        const float* __restrict__ feat,
                                                        u16* __restrict__ seg) {
    int p = blockIdx.x * 256 + threadIdx.x;
    if (p >= NPIX) return;
    int d = depth[p];
    if (d > 0 && d < V && winner[d] == (unsigned)(p + 1)) {
#pragma unroll
        for (int g = 0; g < 3; ++g) {
            uint2 val;
            val.x = pack2(feat[(4 * g + 0) * NPIX + p], feat[(4 * g + 1) * NPIX + p]);
            val.y = pack2(feat[(4 * g + 2) * NPIX + p], feat[(4 * g + 3) * NPIX + p]);
            *(uint2*)(seg + g * GRP_U16 + (size_t)d * 4) = val;
        }
    }
}

// ============================================================
// One-pass LDS-shared avg-pool hole-fill (one group [V][4]).
// GATED: raw loads masked by winner!=0 (volume NOT pre-zeroed).
// Block tile: 4d x 4h x 120w. Phase 1: 3-tap W row-sums for 36 halo rows
// into LDS. Phase 2: 9-row sum, /27, select vs raw, write out-of-place.
// ============================================================
constexpr int FTW = 120;
constexpr int FROWS = 36;

template <bool GATED>
__global__ void __launch_bounds__(256) kz_fillL(const u16* __restrict__ rb,
                                                const unsigned* __restrict__ win,
                                                u16* __restrict__ fb) {
    __shared__ u16 S[FROWS * FTW * 4];   // 34,560 B
    int bid = blockIdx.x;                 // grid: 60*36*2 = 4320
    int wt = bid & 1;
    int t1 = bid >> 1;
    int ht = t1 % 36;
    int dt = t1 / 36;
    int d0 = dt * 4, h0 = ht * 4, w0 = wt * 120;
    int tid = threadIdx.x;

    // Phase 1: 36 rows x 60 voxel-pair tasks
    for (int tt = tid; tt < FROWS * 60; tt += 256) {
        int hr = tt / 60;
        int pt = tt - hr * 60;
        int w = w0 + 2 * pt;
        int d = d0 - 1 + hr / 6;
        int h = h0 - 1 + hr % 6;
        uint4 O = make_uint4(0u, 0u, 0u, 0u);
        if (d >= 0 && d < D0 && h >= 0 && h < H0) {
            size_t row = (size_t)(d * H0 + h) * W0;
            const u16* rp = rb + (row + w) * 4;
            uint4 X = *(const uint4*)(rp);
            if (GATED) {
                uint2 WN = *(const uint2*)(win + row + w);
                if (WN.x == 0u) { X.x = 0u; X.y = 0u; }
                if (WN.y == 0u) { X.z = 0u; X.w = 0u; }
            }
            float x0[4] = {lo16(X.x), hi16(X.x), lo16(X.y), hi16(X.y)};
            float x1[4] = {lo16(X.z), hi16(X.z), lo16(X.w), hi16(X.w)};
            float l[4] = {0.f, 0.f, 0.f, 0.f}, rr[4] = {0.f, 0.f, 0.f, 0.f};
            if (w > 0) {
                uint2 L = *(const uint2*)(rp - 4);
                if (GATED && win[row + w - 1] == 0u) { L.x = 0u; L.y = 0u; }
                l[0] = lo16(L.x); l[1] = hi16(L.x); l[2] = lo16(L.y); l[3] = hi16(L.y);
            }
            if (w < 238) {
                uint2 R = *(const uint2*)(rp + 8);
                if (GATED && win[row + w + 2] == 0u) { R.x = 0u; R.y = 0u; }
                rr[0] = lo16(R.x); rr[1] = hi16(R.x); rr[2] = lo16(R.y); rr[3] = hi16(R.y);
            }
            O.x = pack2(l[0] + x0[0] + x1[0], l[1] + x0[1] + x1[1]);
            O.y = pack2(l[2] + x0[2] + x1[2], l[3] + x0[3] + x1[3]);
            O.z = pack2(x0[0] + x1[0] + rr[0], x0[1] + x1[1] + rr[1]);
            O.w = pack2(x0[2] + x1[2] + rr[2], x0[3] + x1[3] + rr[3]);
        }
        *(uint4*)(S + ((size_t)hr * FTW + 2 * pt) * 4) = O;
    }
    __syncthreads();

    // Phase 2: 16 output rows x 60 voxel-pair tasks
    for (int ot = tid; ot < 16 * 60; ot += 256) {
        int orr = ot / 60;
        int pt = ot - orr * 60;
        int w = w0 + 2 * pt;
        int di = orr >> 2, hi_ = orr & 3;
        int d = d0 + di, h = h0 + hi_;
        float s[8] = {0.f, 0.f, 0.f, 0.f, 0.f, 0.f, 0.f, 0.f};
#pragma unroll
        for (int dd = 0; dd < 3; ++dd) {
#pragma unroll
            for (int dh = 0; dh < 3; ++dh) {
                int hr = (di + dd) * 6 + (hi_ + dh);
                uint4 T = *(const uint4*)(S + ((size_t)hr * FTW + 2 * pt) * 4);
                s[0] += lo16(T.x); s[1] += hi16(T.x); s[2] += lo16(T.y); s[3] += hi16(T.y);
                s[4] += lo16(T.z); s[5] += hi16(T.z); s[6] += lo16(T.w); s[7] += hi16(T.w);
            }
        }
        size_t row = (size_t)(d * H0 + h) * W0;
        size_t gi = (row + w) * 4;
        uint4 Rv = *(const uint4*)(rb + gi);
        if (GATED) {
            uint2 WN = *(const uint2*)(win + row + w);
            if (WN.x == 0u) { Rv.x = 0u; Rv.y = 0u; }
            if (WN.y == 0u) { Rv.z = 0u; Rv.w = 0u; }
        }
        constexpr float inv27 = 1.0f / 27.0f;
        uint4 Ov;
        Ov.x = ((Rv.x & 0x7FFFu) ? (Rv.x & 0xFFFFu) : f2u(s[0] * inv27))
             | ((((Rv.x >> 16) & 0x7FFFu) ? (Rv.x >> 16) : f2u(s[1] * inv27)) << 16);
        Ov.y = ((Rv.y & 0x7FFFu) ? (Rv.y & 0xFFFFu) : f2u(s[2] * inv27))
             | ((((Rv.y >> 16) & 0x7FFFu) ? (Rv.y >> 16) : f2u(s[3] * inv27)) << 16);
        Ov.z = ((Rv.z & 0x7FFFu) ? (Rv.z & 0xFFFFu) : f2u(s[4] * inv27))
             | ((((Rv.z >> 16) & 0x7FFFu) ? (Rv.z >> 16) : f2u(s[5] * inv27)) << 16);
        Ov.w = ((Rv.w & 0x7FFFu) ? (Rv.w & 0xFFFFu) : f2u(s[6] * inv27))
             | ((((Rv.w >> 16) & 0x7FFFu) ? (Rv.w >> 16) : f2u(s[7] * inv27)) << 16);
        *(uint4*)(fb + gi) = Ov;
    }
}

// ============================================================
// Downsample 1 (R12/R13-proven body): conv 12->4 ++ maxpool2, relu
// -> x1 interleaved [N1][16]
// ============================================================
__global__ void __launch_bounds__(256) kz_ds1(const u16* __restrict__ f0g,
                                              const u16* __restrict__ f1g,
                                              const u16* __restrict__ f2g,
                                              const float* __restrict__ w,
                                              float* __restrict__ x1i) {
    __shared__ float wl[4 * 12 * 27];
    __shared__ float pool[12 * 256];
    for (int t = threadIdx.x; t < 4 * 12 * 27; t += 256) wl[t] = w[t];
    __syncthreads();
    int tid = threadIdx.x;
    int o = blockIdx.x * 256 + tid;    // grid exact: N1/256 = 4050
    int wo = o % W1;
    int t  = o / W1;
    int ho = t % H1;
    int d0 = t / H1;
    float acc[4] = {0.f, 0.f, 0.f, 0.f};
#pragma unroll 1
    for (int g = 0; g < 3; ++g) {
        const u16* base = (g == 0) ? f0g : ((g == 1) ? f1g : f2g);
        const float* wg = wl + (4 * g) * 27;
        float mx0 = -1e30f, mx1 = -1e30f, mx2 = -1e30f, mx3 = -1e30f;
#pragma unroll 1
        for (int kd = 0; kd < 3; ++kd) {
            int d2 = 2 * d0 - 1 + kd;
            bool dv = (d2 >= 0 && d2 < D0);
#pragma unroll
            for (int kh = 0; kh < 3; ++kh) {
                int h2 = 2 * ho - 1 + kh;
                bool rvv = dv && (h2 >= 0 && h2 < H0);
                float a0 = 0.f, a1 = 0.f, a2 = 0.f, a3 = 0.f;
                float b0 = 0.f, b1 = 0.f, b2 = 0.f, b3 = 0.f;
                float c0 = 0.f, c1 = 0.f, c2 = 0.f, c3 = 0.f;
                if (rvv) {
                    size_t r2 = (size_t)((d2 * H0 + h2) * W0 + 2 * wo);
                    uint4 AB = *(const uint4*)(base + r2 * 4);
                    b0 = lo16(AB.x); b1 = hi16(AB.x); b2 = lo16(AB.y); b3 = hi16(AB.y);
                    c0 = lo16(AB.z); c1 = hi16(AB.z); c2 = lo16(AB.w); c3 = hi16(AB.w);
                    if (wo > 0) {
                        uint2 P = *(const uint2*)(base + (r2 - 1) * 4);
                        a0 = lo16(P.x); a1 = hi16(P.x); a2 = lo16(P.y); a3 = hi16(P.y);
                    }
                }
                const float* wk = wg + kd * 9 + kh * 3;
#pragma unroll
                for (int m = 0; m < 4; ++m) {
                    const float* wm = wk + m * 324;
                    acc[m] += a0 * wm[0]  + b0 * wm[1]  + c0 * wm[2]
                            + a1 * wm[27] + b1 * wm[28] + c1 * wm[29]
                            + a2 * wm[54] + b2 * wm[55] + c2 * wm[56]
                            + a3 * wm[81] + b3 * wm[82] + c3 * wm[83];
                }
                if (kd >= 1 && kh >= 1) {
                    mx0 = fmaxf(mx0, fmaxf(b0, c0));
                    mx1 = fmaxf(mx1, fmaxf(b1, c1));
                    mx2 = fmaxf(mx2, fmaxf(b2, c2));
                    mx3 = fmaxf(mx3, fmaxf(b3, c3));
                }
            }
        }
        pool[(4 * g + 0) * 256 + tid] = fmaxf(mx0, 0.f);
        pool[(4 * g + 1) * 256 + tid] = fmaxf(mx1, 0.f);
        pool[(4 * g + 2) * 256 + tid] = fmaxf(mx2, 0.f);
        pool[(4 * g + 3) * 256 + tid] = fmaxf(mx3, 0.f);
    }
    float* xo = x1i + (size_t)o * 16;
    *(float4*)(xo)      = make_float4(fmaxf(acc[0], 0.f), fmaxf(acc[1], 0.f),
                                      fmaxf(acc[2], 0.f), fmaxf(acc[3], 0.f));
    *(float4*)(xo + 4)  = make_float4(pool[0 * 256 + tid], pool[1 * 256 + tid],
                                      pool[2 * 256 + tid], pool[3 * 256 + tid]);
    *(float4*)(xo + 8)  = make_float4(pool[4 * 256 + tid], pool[5 * 256 + tid],
                                      pool[6 * 256 + tid], pool[7 * 256 + tid]);
    *(float4*)(xo + 12) = make_float4(pool[8 * 256 + tid], pool[9 * 256 + tid],
                                      pool[10 * 256 + tid], pool[11 * 256 + tid]);
}

// ============================================================
// pw 16->4: x1 interleaved [N1][16] -> y0 interleaved [N1][4], relu
// ============================================================
__global__ void __launch_bounds__(256) kz_pw16to4i(const float* __restrict__ in,
                                                   const float* __restrict__ w,
                                                   float* __restrict__ out) {
    __shared__ float wl[64];
    if (threadIdx.x < 64) wl[threadIdx.x] = w[threadIdx.x];
    __syncthreads();
    int o = blockIdx.x * 256 + threadIdx.x;   // exact
    const float* ip = in + (size_t)o * 16;
    float4 A = *(const float4*)(ip);
    float4 B = *(const float4*)(ip + 4);
    float4 C = *(const float4*)(ip + 8);
    float4 D = *(const float4*)(ip + 12);
    float r[4];
#pragma unroll
    for (int m = 0; m < 4; ++m) {
        const float* wm = wl + m * 16;
        r[m] = A.x * wm[0] + A.y * wm[1] + A.z * wm[2] + A.w * wm[3]
             + B.x * wm[4] + B.y * wm[5] + B.z * wm[6] + B.w * wm[7]
             + C.x * wm[8] + C.y * wm[9] + C.z * wm[10] + C.w * wm[11]
             + D.x * wm[12] + D.y * wm[13] + D.z * wm[14] + D.w * wm[15];
    }
    *(float4*)(out + (size_t)o * 4) = make_float4(fmaxf(r[0], 0.f), fmaxf(r[1], 0.f),
                                                  fmaxf(r[2], 0.f), fmaxf(r[3], 0.f));
}

// ============================================================
// bconv 4ch interleaved [N1][4]: (KD,KH,KW), bias, NADD residuals, relu
// ============================================================
template <int KD, int KH, int KW, int NADD>
__global__ void __launch_bounds__(256) kz_bconv4i(const float* __restrict__ in,
                                                  const float* __restrict__ w,
                                                  const float* __restrict__ b,
                                                  const float* __restrict__ add1,
                                                  const float* __restrict__ add2,
                                                  float* __restrict__ out) {
    constexpr int S = KD * KH * KW;
    __shared__ float wl[16 * S];
    __shared__ float bl[4];
    for (int t = threadIdx.x; t < 16 * S; t += 256) wl[t] = w[t];
    if (threadIdx.x < 4) bl[threadIdx.x] = b[threadIdx.x];
    __syncthreads();
    int o = blockIdx.x * 256 + threadIdx.x;   // exact: N1/256
    int wo = o % W1;
    int t  = o / W1;
    int ho = t % H1;
    int d0 = t / H1;
    float a0 = bl[0], a1 = bl[1], a2 = bl[2], a3 = bl[3];
#pragma unroll
    for (int kd = 0; kd < KD; ++kd) {
        int d2 = d0 + kd - KD / 2;
        if (KD > 1 && (d2 < 0 || d2 >= D1)) continue;
#pragma unroll
        for (int kh = 0; kh < KH; ++kh) {
            int h2 = ho + kh - KH / 2;
            if (KH > 1 && (h2 < 0 || h2 >= H1)) continue;
#pragma unroll
            for (int kw = 0; kw < KW; ++kw) {
                int w2 = wo + kw - KW / 2;
                if (KW > 1 && (w2 < 0 || w2 >= W1)) continue;
                float4 v = *(const float4*)(in + (size_t)((d2 * H1 + h2) * W1 + w2) * 4);
                int tap = (kd * KH + kh) * KW + kw;
                const float* wt = wl + tap;
                a0 += v.x * wt[0 * S] + v.y * wt[1 * S] + v.z * wt[2 * S] + v.w * wt[3 * S];
                a1 += v.x * wt[4 * S] + v.y * wt[5 * S] + v.z * wt[6 * S] + v.w * wt[7 * S];
                a2 += v.x * wt[8 * S] + v.y * wt[9 * S] + v.z * wt[10 * S] + v.w * wt[11 * S];
                a3 += v.x * wt[12 * S] + v.y * wt[13 * S] + v.z * wt[14 * S] + v.w * wt[15 * S];
            }
        }
    }
    if (NADD >= 1) {
        float4 r1 = *(const float4*)(add1 + (size_t)o * 4);
        a0 += r1.x; a1 += r1.y; a2 += r1.z; a3 += r1.w;
    }
    if (NADD >= 2) {
        float4 r2 = *(const float4*)(add2 + (size_t)o * 4);
        a0 += r2.x; a1 += r2.y; a2 += r2.z; a3 += r2.w;
    }
    *(float4*)(out + (size_t)o * 4) = make_float4(fmaxf(a0, 0.f), fmaxf(a1, 0.f),
                                                  fmaxf(a2, 0.f), fmaxf(a3, 0.f));
}

// ============================================================
// FUSED: bconv4 (3,1,3) + bias + 2 residuals + relu -> pw 4->16
//        + residual(x1i) + relu -> x1b PLANAR [16][N1]
// ============================================================
__global__ void __launch_bounds__(256) kz_bconv4i_pw(const float* __restrict__ in,
                                                     const float* __restrict__ w,
                                                     const float* __restrict__ b,
                                                     const float* __restrict__ add1,
                                                     const float* __restrict__ add2,
                                                     const float* __restrict__ wp,
                                                     const float* __restrict__ x1i,
                                                     float* __restrict__ out) {
    constexpr int S = 9;   // 3*1*3
    __shared__ float wl[16 * S];
    __shared__ float bl[4];
    __shared__ float wpl[64];
    for (int t = threadIdx.x; t < 16 * S; t += 256) wl[t] = w[t];
    if (threadIdx.x < 4) bl[threadIdx.x] = b[threadIdx.x];
    if (threadIdx.x < 64) wpl[threadIdx.x] = wp[threadIdx.x];
    __syncthreads();
    int o = blockIdx.x * 256 + threadIdx.x;   // exact
    int wo = o % W1;
    int t  = o / W1;
    int ho = t % H1;
    int d0 = t / H1;
    float a0 = bl[0], a1 = bl[1], a2 = bl[2], a3 = bl[3];
#pragma unroll
    for (int kd = 0; kd < 3; ++kd) {
        int d2 = d0 + kd - 1;
        if (d2 < 0 || d2 >= D1) continue;
#pragma unroll
        for (int kw = 0; kw < 3; ++kw) {
            int w2 = wo + kw - 1;
            if (w2 < 0 || w2 >= W1) continue;
            float4 v = *(const float4*)(in + (size_t)((d2 * H1 + ho) * W1 + w2) * 4);
            int tap = kd * 3 + kw;
            const float* wt = wl + tap;
            a0 += v.x * wt[0 * S] + v.y * wt[1 * S] + v.z * wt[2 * S] + v.w * wt[3 * S];
            a1 += v.x * wt[4 * S] + v.y * wt[5 * S] + v.z * wt[6 * S] + v.w * wt[7 * S];
            a2 += v.x * wt[8 * S] + v.y * wt[9 * S] + v.z * wt[10 * S] + v.w * wt[11 * S];
            a3 += v.x * wt[12 * S] + v.y * wt[13 * S] + v.z * wt[14 * S] + v.w * wt[15 * S];
        }
    }
    float4 r1 = *(const float4*)(add1 + (size_t)o * 4);
    float4 r2 = *(const float4*)(add2 + (size_t)o * 4);
    float y0 = fmaxf(a0 + r1.x + r2.x, 0.f);
    float y1 = fmaxf(a1 + r1.y + r2.y, 0.f);
    float y2 = fmaxf(a2 + r1.z + r2.z, 0.f);
    float y3 = fmaxf(a3 + r1.w + r2.w, 0.f);
    const float* rp = x1i + (size_t)o * 16;
    float4 R0 = *(const float4*)(rp);
    float4 R1 = *(const float4*)(rp + 4);
    float4 R2 = *(const float4*)(rp + 8);
    float4 R3 = *(const float4*)(rp + 12);
    float rr[16] = {R0.x, R0.y, R0.z, R0.w, R1.x, R1.y, R1.z, R1.w,
                    R2.x, R2.y, R2.z, R2.w, R3.x, R3.y, R3.z, R3.w};
#pragma unroll
    for (int m = 0; m < 16; ++m) {
        const float* wm = wpl + m * 4;
        float r = y0 * wm[0] + y1 * wm[1] + y2 * wm[2] + y3 * wm[3] + rr[m];
        out[(size_t)m * N1 + o] = fmaxf(r, 0.f);
    }
}

// ============================================================
// FUSED Downsample 2 + pw 32->8 (R12-proven)
// ============================================================
__global__ void __launch_bounds__(256) kz_ds2f(const float* __restrict__ in,
                                               const float* __restrict__ w,
                                               const float* __restrict__ wz,
                                               float* __restrict__ out,
                                               float* __restrict__ z0i) {
    __shared__ float wl[16 * 16 * 27];
    __shared__ float wzl[256];
    for (int t = threadIdx.x; t < 16 * 16 * 27; t += 256) wl[t] = w[t];
    if (threadIdx.x < 256) wzl[threadIdx.x] = wz[threadIdx.x];
    __syncthreads();
    int o = blockIdx.x * 256 + threadIdx.x;
    if (o >= N2) return;
    int wo = o % W2;
    int t  = o / W2;
    int ho = t % H2;
    int d0 = t / H2;
    float acc[16];
    float zacc[8];
#pragma unroll
    for (int m = 0; m < 16; ++m) acc[m] = 0.f;
#pragma unroll
    for (int m = 0; m < 8; ++m) zacc[m] = 0.f;
#pragma unroll 1
    for (int ci = 0; ci < 16; ++ci) {
        const float* base = in + ci * N1;
        const float* wci = wl + ci * 27;
        float mx = -1e30f;
#pragma unroll 1
        for (int kd = 0; kd < 3; ++kd) {
            int d2 = 2 * d0 - 1 + kd;
            bool dv = (d2 >= 0 && d2 < D1);
#pragma unroll
            for (int kh = 0; kh < 3; ++kh) {
                int h2 = 2 * ho - 1 + kh;
                bool rvv = dv && (h2 >= 0 && h2 < H1);
                float vm1 = 0.f, v0 = 0.f, v1 = 0.f;
                if (rvv) {
                    int r2 = (d2 * H1 + h2) * W1 + 2 * wo;
                    float2 pb = *(const float2*)(base + r2);
                    v0 = pb.x; v1 = pb.y;
                    if (wo > 0) {
                        float2 pa = *(const float2*)(base + r2 - 2);
                        vm1 = pa.y;
                    }
                }
                const float* wk = wci + kd * 9 + kh * 3;
#pragma unroll
                for (int m = 0; m < 16; ++m)
                    acc[m] += vm1 * wk[m * 432] + v0 * wk[m * 432 + 1] + v1 * wk[m * 432 + 2];
                if (kd >= 1 && kh >= 1) mx = fmaxf(mx, fmaxf(v0, v1));
            }
        }
        float pl = fmaxf(mx, 0.f);
        out[(16 + ci) * N2 + o] = pl;
#pragma unroll
        for (int m = 0; m < 8; ++m) zacc[m] += wzl[m * 32 + 16 + ci] * pl;
    }
#pragma unroll
    for (int j = 0; j < 16; ++j) {
        float cj = fmaxf(acc[j], 0.f);
        out[j * N2 + o] = cj;
#pragma unroll
        for (int m = 0; m < 8; ++m) zacc[m] += wzl[m * 32 + j] * cj;
    }
    float* op = z0i + (size_t)o * 8;
    *(float4*)(op)     = make_float4(fmaxf(zacc[0], 0.f), fmaxf(zacc[1], 0.f),
                                     fmaxf(zacc[2], 0.f), fmaxf(zacc[3], 0.f));
    *(float4*)(op + 4) = make_float4(fmaxf(zacc[4], 0.f), fmaxf(zacc[5], 0.f),
                                     fmaxf(zacc[6], 0.f), fmaxf(zacc[7], 0.f));
}

// ============================================================
// bconv 8ch interleaved [N2][8] (R12-proven)
// ============================================================
template <int KD, int KH, int KW, int NADD>
__global__ void __launch_bounds__(256) kz_bconv8i(const float* __restrict__ in,
                                                  const float* __restrict__ w,
                                                  const float* __restrict__ b,
                                                  const float* __restrict__ add1,
                                                  const float* __restrict__ add2,
                                                  float* __restrict__ out) {
    constexpr int S = KD * KH * KW;
    __shared__ float wl[64 * S];
    __shared__ float bl[8];
    for (int t = threadIdx.x; t < 64 * S; t += 256) wl[t] = w[t];
    if (threadIdx.x < 8) bl[threadIdx.x] = b[threadIdx.x];
    __syncthreads();
    int o = blockIdx.x * 256 + threadIdx.x;
    if (o >= N2) return;
    int wo = o % W2;
    int t  = o / W2;
    int ho = t % H2;
    int d0 = t / H2;
    float acc[8];
#pragma unroll
    for (int m = 0; m < 8; ++m) acc[m] = bl[m];
#pragma unroll
    for (int kd = 0; kd < KD; ++kd) {
        int d2 = d0 + kd - KD / 2;
        if (KD > 1 && (d2 < 0 || d2 >= D2)) continue;
#pragma unroll
        for (int kh = 0; kh < KH; ++kh) {
            int h2 = ho + kh - KH / 2;
            if (KH > 1 && (h2 < 0 || h2 >= H2)) continue;
#pragma unroll
            for (int kw = 0; kw < KW; ++kw) {
                int w2 = wo + kw - KW / 2;
                if (KW > 1 && (w2 < 0 || w2 >= W2)) continue;
                const float* vp = in + (size_t)((d2 * H2 + h2) * W2 + w2) * 8;
                float4 v0 = *(const float4*)(vp);
                float4 v1 = *(const float4*)(vp + 4);
                int tap = (kd * KH + kh) * KW + kw;
                const float* wt = wl + tap;
#pragma unroll
                for (int m = 0; m < 8; ++m) {
                    const float* wm = wt + m * 8 * S;
                    acc[m] += v0.x * wm[0] + v0.y * wm[S] + v0.z * wm[2 * S] + v0.w * wm[3 * S]
                            + v1.x * wm[4 * S] + v1.y * wm[5 * S] + v1.z * wm[6 * S] + v1.w * wm[7 * S];
                }
            }
        }
    }
    if (NADD >= 1) {
        const float* ap = add1 + (size_t)o * 8;
        float4 r0 = *(const float4*)(ap), r1 = *(const float4*)(ap + 4);
        acc[0] += r0.x; acc[1] += r0.y; acc[2] += r0.z; acc[3] += r0.w;
        acc[4] += r1.x; acc[5] += r1.y; acc[6] += r1.z; acc[7] += r1.w;
    }
    if (NADD >= 2) {
        const float* ap = add2 + (size_t)o * 8;
        float4 r0 = *(const float4*)(ap), r1 = *(const float4*)(ap + 4);
        acc[0] += r0.x; acc[1] += r0.y; acc[2] += r0.z; acc[3] += r0.w;
        acc[4] += r1.x; acc[5] += r1.y; acc[6] += r1.z; acc[7] += r1.w;
    }
    float* op = out + (size_t)o * 8;
    *(float4*)(op)     = make_float4(fmaxf(acc[0], 0.f), fmaxf(acc[1], 0.f),
                                     fmaxf(acc[2], 0.f), fmaxf(acc[3], 0.f));
    *(float4*)(op + 4) = make_float4(fmaxf(acc[4], 0.f), fmaxf(acc[5], 0.f),
                                     fmaxf(acc[6], 0.f), fmaxf(acc[7], 0.f));
}

// ============================================================
// FUSED: bconv8 (3,1,3) + residuals + relu -> pw 8->32 + residual + relu
// -> d_out planar [32][N2] (R12-proven)
// ============================================================
__global__ void __launch_bounds__(256) kz_bconv8i_pw(const float* __restrict__ in,
                                                     const float* __restrict__ w,
                                                     const float* __restrict__ b,
                                                     const float* __restrict__ add1,
                                                     const float* __restrict__ add2,
                                                     const float* __restrict__ wp,
                                                     const float* __restrict__ resp,
                                                     float* __restrict__ out) {
    constexpr int S = 9;   // 3*1*3
    __shared__ float wl[64 * S];
    __shared__ float bl[8];
    __shared__ float wpl[256];
    for (int t = threadIdx.x; t < 64 * S; t += 256) wl[t] = w[t];
    if (threadIdx.x < 8) bl[threadIdx.x] = b[threadIdx.x];
    if (threadIdx.x < 256) wpl[threadIdx.x] = wp[threadIdx.x];
    __syncthreads();
    int o = blockIdx.x * 256 + threadIdx.x;
    if (o >= N2) return;
    int wo = o % W2;
    int t  = o / W2;
    int ho = t % H2;
    int d0 = t / H2;
    float acc[8];
#pragma unroll
    for (int m = 0; m < 8; ++m) acc[m] = bl[m];
#pragma unroll
    for (int kd = 0; kd < 3; ++kd) {
        int d2 = d0 + kd - 1;
        if (d2 < 0 || d2 >= D2) continue;
#pragma unroll
        for (int kw = 0; kw < 3; ++kw) {
            int w2 = wo + kw - 1;
            if (w2 < 0 || w2 >= W2) continue;
            const float* vp = in + (size_t)((d2 * H2 + ho) * W2 + w2) * 8;
            float4 v0 = *(const float4*)(vp);
            float4 v1 = *(const float4*)(vp + 4);
            int tap = kd * 3 + kw;
            const float* wt = wl + tap;
#pragma unroll
            for (int m = 0; m < 8; ++m) {
                const float* wm = wt + m * 8 * S;
                acc[m] += v0.x * wm[0] + v0.y * wm[S] + v0.z * wm[2 * S] + v0.w * wm[3 * S]
                        + v1.x * wm[4 * S] + v1.y * wm[5 * S] + v1.z * wm[6 * S] + v1.w * wm[7 * S];
            }
        }
    }
    {
        const float* ap = add1 + (size_t)o * 8;
        float4 r0 = *(const float4*)(ap), r1 = *(const float4*)(ap + 4);
        acc[0] += r0.x; acc[1] += r0.y; acc[2] += r0.z; acc[3] += r0.w;
        acc[4] += r1.x; acc[5] += r1.y; acc[6] += r1.z; acc[7] += r1.w;
    }
    {
        const float* ap = add2 + (size_t)o * 8;
        float4 r0 = *(const float4*)(ap), r1 = *(const float4*)(ap + 4);
        acc[0] += r0.x; acc[1] += r0.y; acc[2] += r0.z; acc[3] += r0.w;
        acc[4] += r1.x; acc[5] += r1.y; acc[6] += r1.z; acc[7] += r1.w;
    }
#pragma unroll
    for (int m = 0; m < 8; ++m) acc[m] = fmaxf(acc[m], 0.f);
#pragma unroll
    for (int m = 0; m < 32; ++m) {
        const float* wm = wpl + m * 8;
        float r = acc[0] * wm[0] + acc[1] * wm[1] + acc[2] * wm[2] + acc[3] * wm[3]
                + acc[4] * wm[4] + acc[5] * wm[5] + acc[6] * wm[6] + acc[7] * wm[7];
        r += resp[(size_t)m * N2 + o];
        out[(size_t)m * N2 + o] = fmaxf(r, 0.f);
    }
}

// ============================================================
extern "C" void kernel_launch(void* const* d_in, const int* in_sizes, int n_in,
                              void* d_out, int out_size, void* d_ws, size_t ws_size,
                              hipStream_t stream) {
    const float* feat   = (const float*)d_in[0];
    const int*   depth  = (const int*)d_in[1];
    const float* w_ds1  = (const float*)d_in[2];
    const float* b1_win = (const float*)d_in[3];
    const float* b1w133 = (const float*)d_in[4];
    const float* b1b133 = (const float*)d_in[5];
    const float* b1w331 = (const float*)d_in[6];
    const float* b1b331 = (const float*)d_in[7];
    const float* b1w313 = (const float*)d_in[8];
    const float* b1b313 = (const float*)d_in[9];
    const float* b1wout = (const float*)d_in[10];
    const float* w_ds2  = (const float*)d_in[11];
    const float* b2_win = (const float*)d_in[12];
    const float* b2w133 = (const float*)d_in[13];
    const float* b2b133 = (const float*)d_in[14];
    const float* b2w331 = (const float*)d_in[15];
    const float* b2b331 = (const float*)d_in[16];
    const float* b2w313 = (const float*)d_in[17];
    const float* b2b313 = (const float*)d_in[18];
    const float* b2wout = (const float*)d_in[19];

    char* base = (char*)d_ws;
    // Branch once on ws_size (deterministic every call -> graph-safe).
    const bool bigws = (ws_size >= BIG_WS);

    // --- Region layout ---
    u16* raw0 = (u16*)base;                               // [0, 66.35)
    u16* raw1 = (u16*)(base + GRP_BYTES);                 // [66.35, 132.7)
    u16* raw2 = (u16*)(base + 2 * GRP_BYTES);             // [132.7, 199.07)
    unsigned* winner = (unsigned*)(base + SEG_BYTES);     // [199.07, 232.25)
    // fil0: bigws -> [232.25, 298.6) (winner stays live through fills);
    //       else  -> [199.07, 265.4) (winner dead after scatter; R13 layout)
    u16* fil0 = bigws ? (u16*)(base + SEG_BYTES + WIN_BYTES) : (u16*)(base + SEG_BYTES);
    u16* fil1 = (u16*)base;                               // [0, 66.35)   after raw0 dies
    u16* fil2 = (u16*)(base + GRP_BYTES);                 // [66.35,132.7) after raw1 dies
    float* x1i = (float*)(base + 2 * GRP_BYTES);          // [132.7,199.07) after raw2 dies
    float* y0i = (float*)base;                            // after fil1/fil2 die (post-ds1)
    float* y1i = y0i + 4 * N1;
    float* y2i = y1i + 4 * N1;
    float* x1b = (float*)(base + SEG_BYTES);              // [199.07,265.4) (winner+fil0 dead)
    float* x2  = (float*)base;                            // after y dead
    float* z0i = x2 + 32 * N2;
    float* z1i = z0i + 8 * N2;
    float* z2i = z1i + 8 * N2;

    float* out = (float*)d_out;   // reference output dtype is float32

    // 1. zero: bigws -> winner only (volume reads are winner-gated);
    //          else  -> volume + winner (R13 behavior)
    if (bigws) {
        kz_zero16<<<WCHUNKS / 256, 256, 0, stream>>>((uint4*)winner, WCHUNKS);
    } else {
        kz_zero16<<<ZCHUNKS / 256, 256, 0, stream>>>((uint4*)base, ZCHUNKS);
    }

    // 2. deterministic last-write-wins scatter
    kz_scatter_win  <<<NPIX / 256, 256, 0, stream>>>(depth, winner);
    kz_scatter_write<<<NPIX / 256, 256, 0, stream>>>(depth, winner, feat, raw0);

    // 3. one-pass LDS-shared hole-fill, per group, out-of-place (rotating)
    if (bigws) {
        kz_fillL<true><<<4320, 256, 0, stream>>>(raw0, winner, fil0);
        kz_fillL<true><<<4320, 256, 0, stream>>>(raw1, winner, fil1);
        kz_fillL<true><<<4320, 256, 0, stream>>>(raw2, winner, fil2);
    } else {
        kz_fillL<false><<<4320, 256, 0, stream>>>(raw0, nullptr, fil0);
        kz_fillL<false><<<4320, 256, 0, stream>>>(raw1, nullptr, fil1);
        kz_fillL<false><<<4320, 256, 0, stream>>>(raw2, nullptr, fil2);
    }

    // 4. downsample 1 -> x1 interleaved [N1][16]
    kz_ds1<<<N1 / 256, 256, 0, stream>>>(fil0, fil1, fil2, w_ds1, x1i);

    // 5. bottleneck 1 (interleaved [N1][4]); last bconv fused with pw4->16
    kz_pw16to4i<<<N1 / 256, 256, 0, stream>>>(x1i, b1_win, y0i);
    kz_bconv4i<1, 3, 3, 0><<<N1 / 256, 256, 0, stream>>>(y0i, b1w133, b1b133, nullptr, nullptr, y1i);
    kz_bconv4i<3, 3, 1, 1><<<N1 / 256, 256, 0, stream>>>(y1i, b1w331, b1b331, y1i, nullptr, y2i);
    kz_bconv4i_pw<<<N1 / 256, 256, 0, stream>>>(y2i, b1w313, b1b313, y2i, y1i, b1wout, x1i, x1b);

    // 6. downsample 2 fused with pw32->8 -> x2 planar + z0 interleaved
    kz_ds2f<<<(N2 + 255) / 256, 256, 0, stream>>>(x1b, w_ds2, b2_win, x2, z0i);

    // 7. bottleneck 2 (interleaved [N2][8]); last bconv fused with pw8->32
    kz_bconv8i<1, 3, 3, 0><<<(N2 + 255) / 256, 256, 0, stream>>>(z0i, b2w133, b2b133, nullptr, nullptr, z1i);
    kz_bconv8i<3, 3, 1, 1><<<(N2 + 255) / 256, 256, 0, stream>>>(z1i, b2w331, b2b331, z1i, nullptr, z2i);
    kz_bconv8i_pw<<<(N2 + 255) / 256, 256, 0, stream>>>(z2i, b2w313, b2b313, z2i, z1i, b2wout, x2, out);

    (void)in_sizes; (void)n_in; (void)out_size;
}